// Round 1
// baseline (2062.205 us; speedup 1.0000x reference)
//
#include <hip/hip_runtime.h>
#include <math.h>

#define N_NODES 50000
#define N_EDGES 800000
#define NGRAPH  64
#define CAP_DEG 1024

// ---------------------------------------------------------------------------
// CSR build
// ---------------------------------------------------------------------------
__global__ void degree_kernel(const int* __restrict__ ei, int* __restrict__ counts) {
    int e = blockIdx.x * 256 + threadIdx.x;
    if (e < N_EDGES) atomicAdd(&counts[ei[N_EDGES + e]], 1);
}

// single-wave prefix scan over counts -> offs (exclusive), offs[0]=0, offs[N]=E
__global__ __launch_bounds__(64) void scan_kernel(const int* __restrict__ counts,
                                                  int* __restrict__ offs) {
    int lane = threadIdx.x;
    int carry = 0;
    if (lane == 0) offs[0] = 0;
    for (int base = 0; base < N_NODES; base += 64) {
        int i = base + lane;
        int v = (i < N_NODES) ? counts[i] : 0;
        int incl = v;
        #pragma unroll
        for (int o = 1; o < 64; o <<= 1) {
            int t = __shfl_up(incl, o);
            if (lane >= o) incl += t;
        }
        if (i < N_NODES) offs[i + 1] = carry + incl;
        carry += __shfl(incl, 63);
    }
}

__global__ void copy_int_kernel(const int* __restrict__ a, int* __restrict__ b, int n) {
    int i = blockIdx.x * 256 + threadIdx.x;
    if (i < n) b[i] = a[i];
}

__global__ void scatter_kernel(const int* __restrict__ ei, int* __restrict__ cursor,
                               int* __restrict__ csr) {
    int e = blockIdx.x * 256 + threadIdx.x;
    if (e < N_EDGES) {
        int d = ei[N_EDGES + e];
        int pos = atomicAdd(&cursor[d], 1);
        csr[pos] = ei[e];  // src
    }
}

// ---------------------------------------------------------------------------
// Skip-path fusion: Wc[l] = Ws[l] @ Wt[l]  ([128,256]@[256,128] -> [128,128])
//                   bc[l] = bs[l] @ Wt[l] + bt[l]
// ---------------------------------------------------------------------------
__global__ void wc_kernel(const float* __restrict__ Ws, const float* __restrict__ Wt,
                          float* __restrict__ Wc) {
    int idx = blockIdx.x * 256 + threadIdx.x;       // 2*128*128 = 32768
    int l = idx >> 14, ij = idx & 16383, i = ij >> 7, j = ij & 127;
    const float* a = Ws + (size_t)l * 32768;
    const float* b = Wt + (size_t)l * 32768;
    float s = 0.f;
    for (int k = 0; k < 256; k++) s = fmaf(a[i * 256 + k], b[k * 128 + j], s);
    Wc[idx] = s;
}

__global__ void bc_kernel(const float* __restrict__ bs, const float* __restrict__ Wt,
                          const float* __restrict__ bt, float* __restrict__ bc) {
    int idx = threadIdx.x;                           // 256 threads: 2 layers x 128
    int l = idx >> 7, j = idx & 127;
    const float* b = Wt + (size_t)l * 32768;
    float s = bt[l * 128 + j];
    for (int k = 0; k < 256; k++) s = fmaf(bs[l * 256 + k], b[k * 128 + j], s);
    bc[idx] = s;
}

// ---------------------------------------------------------------------------
// q/k/v projection: [N,128] @ [128,256] + b, three matrices fused
// block = 256 threads, 32 rows per block, thread t owns column t
// ---------------------------------------------------------------------------
__global__ __launch_bounds__(256) void proj_kernel(
    const float* __restrict__ xin,
    const float* __restrict__ W0, const float* __restrict__ b0,
    const float* __restrict__ W1, const float* __restrict__ b1,
    const float* __restrict__ W2, const float* __restrict__ b2,
    float* __restrict__ o0, float* __restrict__ o1, float* __restrict__ o2) {
    __shared__ float xs[32 * 128];
    int n0 = blockIdx.x * 32;
    int rows = min(32, N_NODES - n0);
    int t = threadIdx.x;
    for (int i = t; i < rows * 128; i += 256) xs[i] = xin[(size_t)n0 * 128 + i];
    __syncthreads();

    const float* Wm[3] = {W0, W1, W2};
    const float* bm[3] = {b0, b1, b2};
    float*       om[3] = {o0, o1, o2};
    for (int mm = 0; mm < 3; mm++) {
        const float* __restrict__ W = Wm[mm];
        float acc[32];
        #pragma unroll
        for (int r = 0; r < 32; r++) acc[r] = 0.f;
        for (int k4 = 0; k4 < 128; k4 += 4) {
            float w0 = W[(k4 + 0) * 256 + t];
            float w1 = W[(k4 + 1) * 256 + t];
            float w2 = W[(k4 + 2) * 256 + t];
            float w3 = W[(k4 + 3) * 256 + t];
            #pragma unroll
            for (int r = 0; r < 32; r++) {
                const float4 xv = *(const float4*)&xs[r * 128 + k4];  // broadcast
                acc[r] = fmaf(xv.x, w0, fmaf(xv.y, w1, fmaf(xv.z, w2, fmaf(xv.w, w3, acc[r]))));
            }
        }
        float bb = bm[mm][t];
        float* o = om[mm];
        for (int r = 0; r < rows; r++) o[(size_t)(n0 + r) * 256 + t] = acc[r] + bb;
    }
}

// ---------------------------------------------------------------------------
// Attention: one wave per destination node. Writes h (= attn out) over q buffer.
// q/hout intentionally NOT restrict (they alias).
// ---------------------------------------------------------------------------
__global__ __launch_bounds__(64) void attn_kernel(
    const float* q, const float* __restrict__ kk, const float* __restrict__ vv,
    const int* __restrict__ offs, const int* __restrict__ csr, float* hout) {
    __shared__ float slog[2 * CAP_DEG];
    const float SCALE = 0.08838834764831845f;  // 1/sqrt(128)
    int n = blockIdx.x;
    int lane = threadIdx.x;
    const float* qr = q + (size_t)n * 256;
    float q0 = qr[lane], q1 = qr[64 + lane], q2 = qr[128 + lane], q3 = qr[192 + lane];
    int beg = offs[n], end = offs[n + 1];

    auto logits = [&](int s, float& l0, float& l1) {
        const float* kr = kk + (size_t)s * 256;
        float p0 = q0 * kr[lane] + q1 * kr[64 + lane];
        float p1 = q2 * kr[128 + lane] + q3 * kr[192 + lane];
        #pragma unroll
        for (int o = 32; o >= 1; o >>= 1) {
            p0 += __shfl_xor(p0, o);
            p1 += __shfl_xor(p1, o);
        }
        l0 = p0 * SCALE;
        l1 = p1 * SCALE;
    };

    // pass 1: logits + running max
    float m0 = -1e30f, m1 = -1e30f;
    for (int j = beg; j < end; j++) {
        float l0, l1;
        logits(csr[j], l0, l1);
        int jj = j - beg;
        if (jj < CAP_DEG && lane == 0) { slog[2 * jj] = l0; slog[2 * jj + 1] = l1; }
        m0 = fmaxf(m0, l0);
        m1 = fmaxf(m1, l1);
    }
    // pass 2: denom
    float d0 = 0.f, d1 = 0.f;
    for (int j = beg; j < end; j++) {
        int jj = j - beg;
        float l0, l1;
        if (jj < CAP_DEG) { l0 = slog[2 * jj]; l1 = slog[2 * jj + 1]; }
        else logits(csr[j], l0, l1);
        d0 += __expf(l0 - m0);
        d1 += __expf(l1 - m1);
    }
    float inv0 = 1.f / (d0 + 1e-16f), inv1 = 1.f / (d1 + 1e-16f);
    // pass 3: weighted accumulate of v[src]
    float a0 = 0.f, a1 = 0.f, a2 = 0.f, a3 = 0.f;
    for (int j = beg; j < end; j++) {
        int jj = j - beg;
        float l0, l1;
        if (jj < CAP_DEG) { l0 = slog[2 * jj]; l1 = slog[2 * jj + 1]; }
        else logits(csr[j], l0, l1);
        float w0 = __expf(l0 - m0) * inv0;
        float w1 = __expf(l1 - m1) * inv1;
        const float* vr = vv + (size_t)csr[j] * 256;
        a0 = fmaf(w0, vr[lane], a0);
        a1 = fmaf(w0, vr[64 + lane], a1);
        a2 = fmaf(w1, vr[128 + lane], a2);
        a3 = fmaf(w1, vr[192 + lane], a3);
    }
    float* ho = hout + (size_t)n * 256;
    ho[lane] = a0;
    ho[64 + lane] = a1;
    ho[128 + lane] = a2;
    ho[192 + lane] = a3;
}

// ---------------------------------------------------------------------------
// x_next = relu( h @ Wt  +  x @ Wc  +  bc )    (skip path folded into Wc/bc)
// xin/xout may alias (in-place, tile staged in LDS first) -> no restrict.
// ---------------------------------------------------------------------------
__global__ __launch_bounds__(256) void out_linear_kernel(
    const float* __restrict__ h, const float* xin,
    const float* __restrict__ Wt_, const float* __restrict__ Wc,
    const float* __restrict__ bc, float* xout) {
    __shared__ float hs[32 * 256];
    __shared__ float xs[32 * 128];
    int n0 = blockIdx.x * 32;
    int rows = min(32, N_NODES - n0);
    int t = threadIdx.x;
    for (int i = t; i < rows * 256; i += 256) hs[i] = h[(size_t)n0 * 256 + i];
    for (int i = t; i < rows * 128; i += 256) xs[i] = xin[(size_t)n0 * 128 + i];
    __syncthreads();

    int col = t & 127, rg = t >> 7;
    float acc[16];
    #pragma unroll
    for (int r = 0; r < 16; r++) acc[r] = 0.f;

    for (int k4 = 0; k4 < 256; k4 += 4) {
        float w0 = Wt_[(k4 + 0) * 128 + col];
        float w1 = Wt_[(k4 + 1) * 128 + col];
        float w2 = Wt_[(k4 + 2) * 128 + col];
        float w3 = Wt_[(k4 + 3) * 128 + col];
        #pragma unroll
        for (int r = 0; r < 16; r++) {
            const float4 xv = *(const float4*)&hs[(rg * 16 + r) * 256 + k4];
            acc[r] = fmaf(xv.x, w0, fmaf(xv.y, w1, fmaf(xv.z, w2, fmaf(xv.w, w3, acc[r]))));
        }
    }
    for (int k4 = 0; k4 < 128; k4 += 4) {
        float w0 = Wc[(k4 + 0) * 128 + col];
        float w1 = Wc[(k4 + 1) * 128 + col];
        float w2 = Wc[(k4 + 2) * 128 + col];
        float w3 = Wc[(k4 + 3) * 128 + col];
        #pragma unroll
        for (int r = 0; r < 16; r++) {
            const float4 xv = *(const float4*)&xs[(rg * 16 + r) * 128 + k4];
            acc[r] = fmaf(xv.x, w0, fmaf(xv.y, w1, fmaf(xv.z, w2, fmaf(xv.w, w3, acc[r]))));
        }
    }
    float bb = bc[col];
    for (int r = 0; r < 16; r++) {
        int r2 = rg * 16 + r;
        if (r2 < rows) xout[(size_t)(n0 + r2) * 128 + col] = fmaxf(acc[r] + bb, 0.f);
    }
}

// ---------------------------------------------------------------------------
// Pooling: relu output => values >= 0 => uint atomicMax is order-correct
// ---------------------------------------------------------------------------
__global__ void pool_count_kernel(const int* __restrict__ gi, int* __restrict__ pcnt) {
    int i = blockIdx.x * 256 + threadIdx.x;
    if (i < N_NODES) atomicAdd(&pcnt[gi[i]], 1);
}

__global__ void pool_accum_kernel(const float* __restrict__ x, const int* __restrict__ gi,
                                  float* __restrict__ psum, unsigned* __restrict__ pmax) {
    int idx = blockIdx.x * 256 + threadIdx.x;
    if (idx >= N_NODES * 128) return;
    int n = idx >> 7, d = idx & 127;
    int g = gi[n];
    float v = x[idx];
    atomicAdd(&psum[g * 128 + d], v);
    atomicMax(&pmax[g * 128 + d], __float_as_uint(v));
}

__global__ void pool_final_kernel(const float* __restrict__ psum, const unsigned* __restrict__ pmax,
                                  const int* __restrict__ pcnt, float* __restrict__ out) {
    int idx = blockIdx.x * 256 + threadIdx.x;
    if (idx >= NGRAPH * 384) return;
    int g = idx / 384, c = idx % 384;
    float r;
    if (c < 128)       r = __uint_as_float(pmax[g * 128 + c]);
    else if (c < 256)  r = psum[g * 128 + (c - 128)] / fmaxf((float)pcnt[g], 1.f);
    else               r = psum[g * 128 + (c - 256)];
    out[idx] = r;
}

// ---------------------------------------------------------------------------
extern "C" void kernel_launch(void* const* d_in, const int* in_sizes, int n_in,
                              void* d_out, int out_size, void* d_ws, size_t ws_size,
                              hipStream_t stream) {
    const float* x   = (const float*)d_in[0];
    const int*   ei  = (const int*)d_in[1];
    const int*   gi  = (const int*)d_in[2];
    const float* Wq  = (const float*)d_in[3];
    const float* bq  = (const float*)d_in[4];
    const float* Wk  = (const float*)d_in[5];
    const float* bk  = (const float*)d_in[6];
    const float* Wv  = (const float*)d_in[7];
    const float* bv  = (const float*)d_in[8];
    const float* Wsk = (const float*)d_in[9];
    const float* bsk = (const float*)d_in[10];
    const float* Wt  = (const float*)d_in[11];
    const float* bt  = (const float*)d_in[12];
    float* out = (float*)d_out;

    char* p = (char*)d_ws;
    auto take = [&](size_t bytes) -> char* {
        char* r = p;
        p += (bytes + 255) & ~(size_t)255;
        return r;
    };
    float*    qbuf   = (float*)take((size_t)N_NODES * 256 * 4);  // doubles as attn-out h
    float*    kbuf   = (float*)take((size_t)N_NODES * 256 * 4);
    float*    vbuf   = (float*)take((size_t)N_NODES * 256 * 4);
    float*    x1     = (float*)take((size_t)N_NODES * 128 * 4);
    float*    Wc     = (float*)take(2 * 128 * 128 * 4);
    float*    bc     = (float*)take(2 * 128 * 4);
    int*      counts = (int*)take((size_t)N_NODES * 4);
    int*      offs   = (int*)take((size_t)(N_NODES + 1) * 4);
    int*      cursor = (int*)take((size_t)N_NODES * 4);
    int*      csr    = (int*)take((size_t)N_EDGES * 4);
    float*    psum   = (float*)take(NGRAPH * 128 * 4);
    unsigned* pmax   = (unsigned*)take(NGRAPH * 128 * 4);
    int*      pcnt   = (int*)take(NGRAPH * 4);

    const int EB = (N_EDGES + 255) / 256;          // 3125
    const int NB = (N_NODES + 255) / 256;          // 196
    const int TB = (N_NODES + 31) / 32;            // 1563

    // ---- CSR build (shared by both layers) ----
    hipMemsetAsync(counts, 0, (size_t)N_NODES * 4, stream);
    degree_kernel<<<EB, 256, 0, stream>>>(ei, counts);
    scan_kernel<<<1, 64, 0, stream>>>(counts, offs);
    copy_int_kernel<<<NB, 256, 0, stream>>>(offs, cursor, N_NODES);
    scatter_kernel<<<EB, 256, 0, stream>>>(ei, cursor, csr);

    // ---- skip-path fusion ----
    wc_kernel<<<128, 256, 0, stream>>>(Wsk, Wt, Wc);
    bc_kernel<<<1, 256, 0, stream>>>(bsk, Wt, bt, bc);

    // ---- layer 0 ----
    proj_kernel<<<TB, 256, 0, stream>>>(x, Wq, bq, Wk, bk, Wv, bv, qbuf, kbuf, vbuf);
    attn_kernel<<<N_NODES, 64, 0, stream>>>(qbuf, kbuf, vbuf, offs, csr, qbuf);
    out_linear_kernel<<<TB, 256, 0, stream>>>(qbuf, x, Wt, Wc, bc, x1);

    // ---- layer 1 ----
    proj_kernel<<<TB, 256, 0, stream>>>(x1, Wq + 32768, bq + 256, Wk + 32768, bk + 256,
                                        Wv + 32768, bv + 256, qbuf, kbuf, vbuf);
    attn_kernel<<<N_NODES, 64, 0, stream>>>(qbuf, kbuf, vbuf, offs, csr, qbuf);
    out_linear_kernel<<<TB, 256, 0, stream>>>(qbuf, x1, Wt + 32768, Wc + 16384, bc + 128, x1);

    // ---- pooling ----
    hipMemsetAsync(psum, 0, NGRAPH * 128 * 4, stream);
    hipMemsetAsync(pmax, 0, NGRAPH * 128 * 4, stream);
    hipMemsetAsync(pcnt, 0, NGRAPH * 4, stream);
    pool_count_kernel<<<NB, 256, 0, stream>>>(gi, pcnt);
    pool_accum_kernel<<<(N_NODES * 128 + 255) / 256, 256, 0, stream>>>(x1, gi, psum, pmax);
    pool_final_kernel<<<(NGRAPH * 384 + 255) / 256, 256, 0, stream>>>(psum, pmax, pcnt, out);
}

// Round 2
// 1711.354 us; speedup vs baseline: 1.2050x; 1.2050x over previous
//
#include <hip/hip_runtime.h>
#include <math.h>

#define N_NODES 50000
#define N_EDGES 800000
#define NGRAPH  64
#define CAP_DEG 256
#define SCAN_BLOCKS ((N_NODES + 255) / 256)   // 196

// ---------------------------------------------------------------------------
// CSR build
// ---------------------------------------------------------------------------
__global__ void degree_kernel(const int* __restrict__ ei, int* __restrict__ counts) {
    int e = blockIdx.x * 256 + threadIdx.x;
    if (e < N_EDGES) atomicAdd(&counts[ei[N_EDGES + e]], 1);
}

// Hierarchical scan: (1) per-block sums, (2) scan 196 sums, (3) per-block scan.
__global__ __launch_bounds__(256) void block_sum_kernel(const int* __restrict__ counts,
                                                        int* __restrict__ bsum) {
    int i = blockIdx.x * 256 + threadIdx.x;
    int v = (i < N_NODES) ? counts[i] : 0;
    #pragma unroll
    for (int o = 32; o >= 1; o >>= 1) v += __shfl_xor(v, o);
    __shared__ int ws[4];
    if ((threadIdx.x & 63) == 0) ws[threadIdx.x >> 6] = v;
    __syncthreads();
    if (threadIdx.x == 0) bsum[blockIdx.x] = ws[0] + ws[1] + ws[2] + ws[3];
}

__global__ __launch_bounds__(256) void scan_bsum_kernel(const int* __restrict__ bsum,
                                                        int* __restrict__ boff) {
    int t = threadIdx.x;
    int v = (t < SCAN_BLOCKS) ? bsum[t] : 0;
    int lane = t & 63, wid = t >> 6;
    int incl = v;
    #pragma unroll
    for (int o = 1; o < 64; o <<= 1) {
        int tv = __shfl_up(incl, o);
        if (lane >= o) incl += tv;
    }
    __shared__ int wsum[4];
    if (lane == 63) wsum[wid] = incl;
    __syncthreads();
    int add = 0;
    for (int w = 0; w < wid; w++) add += wsum[w];
    if (t < SCAN_BLOCKS) boff[t] = add + incl - v;   // exclusive
}

__global__ __launch_bounds__(256) void block_scan_kernel(const int* __restrict__ counts,
                                                         const int* __restrict__ boff,
                                                         int* __restrict__ offs,
                                                         int* __restrict__ cursor) {
    int i = blockIdx.x * 256 + threadIdx.x;
    int v = (i < N_NODES) ? counts[i] : 0;
    int lane = threadIdx.x & 63, wid = threadIdx.x >> 6;
    int incl = v;
    #pragma unroll
    for (int o = 1; o < 64; o <<= 1) {
        int tv = __shfl_up(incl, o);
        if (lane >= o) incl += tv;
    }
    __shared__ int wsum[4];
    if (lane == 63) wsum[wid] = incl;
    __syncthreads();
    int add = boff[blockIdx.x];
    for (int w = 0; w < wid; w++) add += wsum[w];
    if (i < N_NODES) {
        offs[i + 1] = add + incl;
        cursor[i]   = add + incl - v;
    }
    if (i == 0) offs[0] = 0;
}

__global__ void scatter_kernel(const int* __restrict__ ei, int* __restrict__ cursor,
                               int* __restrict__ csr) {
    int e = blockIdx.x * 256 + threadIdx.x;
    if (e < N_EDGES) {
        int d = ei[N_EDGES + e];
        int pos = atomicAdd(&cursor[d], 1);
        csr[pos] = ei[e];  // src
    }
}

// ---------------------------------------------------------------------------
// Skip-path fusion: Wc[l] = Ws[l] @ Wt[l], bc[l] = bs[l] @ Wt[l] + bt[l]
// ---------------------------------------------------------------------------
__global__ void wc_kernel(const float* __restrict__ Ws, const float* __restrict__ Wt,
                          float* __restrict__ Wc) {
    int idx = blockIdx.x * 256 + threadIdx.x;       // 2*128*128 = 32768
    int l = idx >> 14, ij = idx & 16383, i = ij >> 7, j = ij & 127;
    const float* a = Ws + (size_t)l * 32768;
    const float* b = Wt + (size_t)l * 32768;
    float s = 0.f;
    for (int k = 0; k < 256; k++) s = fmaf(a[i * 256 + k], b[k * 128 + j], s);
    Wc[idx] = s;
}

__global__ void bc_kernel(const float* __restrict__ bs, const float* __restrict__ Wt,
                          const float* __restrict__ bt, float* __restrict__ bc) {
    int idx = threadIdx.x;                           // 2 layers x 128
    int l = idx >> 7, j = idx & 127;
    const float* b = Wt + (size_t)l * 32768;
    float s = bt[l * 128 + j];
    for (int k = 0; k < 256; k++) s = fmaf(bs[l * 256 + k], b[k * 128 + j], s);
    bc[idx] = s;
}

// ---------------------------------------------------------------------------
// q/k/v projection: [N,128] @ [128,256] + b, three matrices fused
// ---------------------------------------------------------------------------
__global__ __launch_bounds__(256) void proj_kernel(
    const float* __restrict__ xin,
    const float* __restrict__ W0, const float* __restrict__ b0,
    const float* __restrict__ W1, const float* __restrict__ b1,
    const float* __restrict__ W2, const float* __restrict__ b2,
    float* __restrict__ o0, float* __restrict__ o1, float* __restrict__ o2) {
    __shared__ float xs[32 * 128];
    int n0 = blockIdx.x * 32;
    int rows = min(32, N_NODES - n0);
    int t = threadIdx.x;
    for (int i = t; i < rows * 128; i += 256) xs[i] = xin[(size_t)n0 * 128 + i];
    __syncthreads();

    const float* Wm[3] = {W0, W1, W2};
    const float* bm[3] = {b0, b1, b2};
    float*       om[3] = {o0, o1, o2};
    for (int mm = 0; mm < 3; mm++) {
        const float* __restrict__ W = Wm[mm];
        float acc[32];
        #pragma unroll
        for (int r = 0; r < 32; r++) acc[r] = 0.f;
        for (int k4 = 0; k4 < 128; k4 += 4) {
            float w0 = W[(k4 + 0) * 256 + t];
            float w1 = W[(k4 + 1) * 256 + t];
            float w2 = W[(k4 + 2) * 256 + t];
            float w3 = W[(k4 + 3) * 256 + t];
            #pragma unroll
            for (int r = 0; r < 32; r++) {
                const float4 xv = *(const float4*)&xs[r * 128 + k4];  // broadcast
                acc[r] = fmaf(xv.x, w0, fmaf(xv.y, w1, fmaf(xv.z, w2, fmaf(xv.w, w3, acc[r]))));
            }
        }
        float bb = bm[mm][t];
        float* o = om[mm];
        for (int r = 0; r < rows; r++) o[(size_t)(n0 + r) * 256 + t] = acc[r] + bb;
    }
}

// ---------------------------------------------------------------------------
// Attention, float4 layout: lane i holds row elements [4i,4i+4). Head 0 lives
// in lanes 0..31, head 1 in lanes 32..63. One dwordx4 gather per lane per row.
// Dot reduce: 5-stage intra-half butterfly + one xor-32 exchange.
// Two passes: (1) logits -> LDS + max, (2) exp-weighted v accumulate + denom.
// Writes h over the q buffer (row-exclusive, safe).
// ---------------------------------------------------------------------------
__global__ __launch_bounds__(64) void attn_kernel(
    const float* q, const float* __restrict__ kk, const float* __restrict__ vv,
    const int* __restrict__ offs, const int* __restrict__ csr, float* hout) {
    __shared__ float slog[2 * CAP_DEG];
    const float SCALE = 0.08838834764831845f;  // 1/sqrt(128)
    int n = blockIdx.x, lane = threadIdx.x;
    float4 q4 = ((const float4*)(q + (size_t)n * 256))[lane];
    int beg = offs[n], end = offs[n + 1], deg = end - beg;
    bool lo = lane < 32;

    float4 acc = make_float4(0.f, 0.f, 0.f, 0.f);
    float d0 = 0.f, d1 = 0.f;
    float m0 = -1e30f, m1 = -1e30f;

    if (deg <= CAP_DEG) {
        // ---- pass 1: logits -> LDS, running max ----
        int j = 0;
        for (; j + 2 <= deg; j += 2) {
            int s0 = csr[beg + j], s1 = csr[beg + j + 1];
            float4 ka = ((const float4*)(kk + (size_t)s0 * 256))[lane];
            float4 kb = ((const float4*)(kk + (size_t)s1 * 256))[lane];
            float pa = q4.x * ka.x + q4.y * ka.y + q4.z * ka.z + q4.w * ka.w;
            float pb = q4.x * kb.x + q4.y * kb.y + q4.z * kb.z + q4.w * kb.w;
            #pragma unroll
            for (int o = 16; o >= 1; o >>= 1) {
                pa += __shfl_xor(pa, o);
                pb += __shfl_xor(pb, o);
            }
            float xa = __shfl_xor(pa, 32), xb = __shfl_xor(pb, 32);
            float la0 = (lo ? pa : xa) * SCALE, la1 = (lo ? xa : pa) * SCALE;
            float lb0 = (lo ? pb : xb) * SCALE, lb1 = (lo ? xb : pb) * SCALE;
            if (lane == 0) {
                slog[2 * j]     = la0;
                slog[2 * j + 1] = la1;
                slog[2 * j + 2] = lb0;
                slog[2 * j + 3] = lb1;
            }
            m0 = fmaxf(m0, fmaxf(la0, lb0));
            m1 = fmaxf(m1, fmaxf(la1, lb1));
        }
        if (j < deg) {
            int s0 = csr[beg + j];
            float4 ka = ((const float4*)(kk + (size_t)s0 * 256))[lane];
            float pa = q4.x * ka.x + q4.y * ka.y + q4.z * ka.z + q4.w * ka.w;
            #pragma unroll
            for (int o = 16; o >= 1; o >>= 1) pa += __shfl_xor(pa, o);
            float xa = __shfl_xor(pa, 32);
            float la0 = (lo ? pa : xa) * SCALE, la1 = (lo ? xa : pa) * SCALE;
            if (lane == 0) { slog[2 * j] = la0; slog[2 * j + 1] = la1; }
            m0 = fmaxf(m0, la0);
            m1 = fmaxf(m1, la1);
        }
        // ---- pass 2: exp-weighted v accumulate + denom (normalize after) ----
        j = 0;
        for (; j + 2 <= deg; j += 2) {
            float ea0 = __expf(slog[2 * j]     - m0), ea1 = __expf(slog[2 * j + 1] - m1);
            float eb0 = __expf(slog[2 * j + 2] - m0), eb1 = __expf(slog[2 * j + 3] - m1);
            d0 += ea0 + eb0;
            d1 += ea1 + eb1;
            int s0 = csr[beg + j], s1 = csr[beg + j + 1];
            float4 va = ((const float4*)(vv + (size_t)s0 * 256))[lane];
            float4 vb = ((const float4*)(vv + (size_t)s1 * 256))[lane];
            float wa = lo ? ea0 : ea1, wb = lo ? eb0 : eb1;
            acc.x = fmaf(wa, va.x, fmaf(wb, vb.x, acc.x));
            acc.y = fmaf(wa, va.y, fmaf(wb, vb.y, acc.y));
            acc.z = fmaf(wa, va.z, fmaf(wb, vb.z, acc.z));
            acc.w = fmaf(wa, va.w, fmaf(wb, vb.w, acc.w));
        }
        if (j < deg) {
            float ea0 = __expf(slog[2 * j] - m0), ea1 = __expf(slog[2 * j + 1] - m1);
            d0 += ea0;
            d1 += ea1;
            int s0 = csr[beg + j];
            float4 va = ((const float4*)(vv + (size_t)s0 * 256))[lane];
            float wa = lo ? ea0 : ea1;
            acc.x = fmaf(wa, va.x, acc.x);
            acc.y = fmaf(wa, va.y, acc.y);
            acc.z = fmaf(wa, va.z, acc.z);
            acc.w = fmaf(wa, va.w, acc.w);
        }
    } else {
        // ---- fallback for deg > CAP_DEG: recompute logits ----
        auto elog = [&](int s, float& l0, float& l1) {
            float4 k4 = ((const float4*)(kk + (size_t)s * 256))[lane];
            float p = q4.x * k4.x + q4.y * k4.y + q4.z * k4.z + q4.w * k4.w;
            #pragma unroll
            for (int o = 16; o >= 1; o >>= 1) p += __shfl_xor(p, o);
            float x = __shfl_xor(p, 32);
            l0 = (lo ? p : x) * SCALE;
            l1 = (lo ? x : p) * SCALE;
        };
        for (int j = 0; j < deg; j++) {
            float l0, l1;
            elog(csr[beg + j], l0, l1);
            m0 = fmaxf(m0, l0);
            m1 = fmaxf(m1, l1);
        }
        for (int j = 0; j < deg; j++) {
            float l0, l1;
            int s = csr[beg + j];
            elog(s, l0, l1);
            float e0 = __expf(l0 - m0), e1 = __expf(l1 - m1);
            d0 += e0;
            d1 += e1;
            float4 va = ((const float4*)(vv + (size_t)s * 256))[lane];
            float w = lo ? e0 : e1;
            acc.x = fmaf(w, va.x, acc.x);
            acc.y = fmaf(w, va.y, acc.y);
            acc.z = fmaf(w, va.z, acc.z);
            acc.w = fmaf(w, va.w, acc.w);
        }
    }
    float inv = lo ? (1.f / (d0 + 1e-16f)) : (1.f / (d1 + 1e-16f));
    acc.x *= inv; acc.y *= inv; acc.z *= inv; acc.w *= inv;
    ((float4*)(hout + (size_t)n * 256))[lane] = acc;
}

// ---------------------------------------------------------------------------
// x_next = relu( h @ Wt  +  x @ Wc  +  bc )    (skip path folded into Wc/bc)
// ---------------------------------------------------------------------------
__global__ __launch_bounds__(256) void out_linear_kernel(
    const float* __restrict__ h, const float* xin,
    const float* __restrict__ Wt_, const float* __restrict__ Wc,
    const float* __restrict__ bc, float* xout) {
    __shared__ float hs[32 * 256];
    __shared__ float xs[32 * 128];
    int n0 = blockIdx.x * 32;
    int rows = min(32, N_NODES - n0);
    int t = threadIdx.x;
    for (int i = t; i < rows * 256; i += 256) hs[i] = h[(size_t)n0 * 256 + i];
    for (int i = t; i < rows * 128; i += 256) xs[i] = xin[(size_t)n0 * 128 + i];
    __syncthreads();

    int col = t & 127, rg = t >> 7;
    float acc[16];
    #pragma unroll
    for (int r = 0; r < 16; r++) acc[r] = 0.f;

    for (int k4 = 0; k4 < 256; k4 += 4) {
        float w0 = Wt_[(k4 + 0) * 128 + col];
        float w1 = Wt_[(k4 + 1) * 128 + col];
        float w2 = Wt_[(k4 + 2) * 128 + col];
        float w3 = Wt_[(k4 + 3) * 128 + col];
        #pragma unroll
        for (int r = 0; r < 16; r++) {
            const float4 xv = *(const float4*)&hs[(rg * 16 + r) * 256 + k4];
            acc[r] = fmaf(xv.x, w0, fmaf(xv.y, w1, fmaf(xv.z, w2, fmaf(xv.w, w3, acc[r]))));
        }
    }
    for (int k4 = 0; k4 < 128; k4 += 4) {
        float w0 = Wc[(k4 + 0) * 128 + col];
        float w1 = Wc[(k4 + 1) * 128 + col];
        float w2 = Wc[(k4 + 2) * 128 + col];
        float w3 = Wc[(k4 + 3) * 128 + col];
        #pragma unroll
        for (int r = 0; r < 16; r++) {
            const float4 xv = *(const float4*)&xs[(rg * 16 + r) * 128 + k4];
            acc[r] = fmaf(xv.x, w0, fmaf(xv.y, w1, fmaf(xv.z, w2, fmaf(xv.w, w3, acc[r]))));
        }
    }
    float bb = bc[col];
    for (int r = 0; r < 16; r++) {
        int r2 = rg * 16 + r;
        if (r2 < rows) xout[(size_t)(n0 + r2) * 128 + col] = fmaxf(acc[r] + bb, 0.f);
    }
}

// ---------------------------------------------------------------------------
// Pooling: relu output => values >= 0 => uint atomicMax is order-correct
// ---------------------------------------------------------------------------
__global__ void pool_count_kernel(const int* __restrict__ gi, int* __restrict__ pcnt) {
    int i = blockIdx.x * 256 + threadIdx.x;
    if (i < N_NODES) atomicAdd(&pcnt[gi[i]], 1);
}

__global__ void pool_accum_kernel(const float* __restrict__ x, const int* __restrict__ gi,
                                  float* __restrict__ psum, unsigned* __restrict__ pmax) {
    int idx = blockIdx.x * 256 + threadIdx.x;
    if (idx >= N_NODES * 128) return;
    int n = idx >> 7, d = idx & 127;
    int g = gi[n];
    float v = x[idx];
    atomicAdd(&psum[g * 128 + d], v);
    atomicMax(&pmax[g * 128 + d], __float_as_uint(v));
}

__global__ void pool_final_kernel(const float* __restrict__ psum, const unsigned* __restrict__ pmax,
                                  const int* __restrict__ pcnt, float* __restrict__ out) {
    int idx = blockIdx.x * 256 + threadIdx.x;
    if (idx >= NGRAPH * 384) return;
    int g = idx / 384, c = idx % 384;
    float r;
    if (c < 128)       r = __uint_as_float(pmax[g * 128 + c]);
    else if (c < 256)  r = psum[g * 128 + (c - 128)] / fmaxf((float)pcnt[g], 1.f);
    else               r = psum[g * 128 + (c - 256)];
    out[idx] = r;
}

// ---------------------------------------------------------------------------
extern "C" void kernel_launch(void* const* d_in, const int* in_sizes, int n_in,
                              void* d_out, int out_size, void* d_ws, size_t ws_size,
                              hipStream_t stream) {
    const float* x   = (const float*)d_in[0];
    const int*   ei  = (const int*)d_in[1];
    const int*   gi  = (const int*)d_in[2];
    const float* Wq  = (const float*)d_in[3];
    const float* bq  = (const float*)d_in[4];
    const float* Wk  = (const float*)d_in[5];
    const float* bk  = (const float*)d_in[6];
    const float* Wv  = (const float*)d_in[7];
    const float* bv  = (const float*)d_in[8];
    const float* Wsk = (const float*)d_in[9];
    const float* bsk = (const float*)d_in[10];
    const float* Wt  = (const float*)d_in[11];
    const float* bt  = (const float*)d_in[12];
    float* out = (float*)d_out;

    char* p = (char*)d_ws;
    auto take = [&](size_t bytes) -> char* {
        char* r = p;
        p += (bytes + 255) & ~(size_t)255;
        return r;
    };
    float*    qbuf   = (float*)take((size_t)N_NODES * 256 * 4);  // doubles as attn-out h
    float*    kbuf   = (float*)take((size_t)N_NODES * 256 * 4);
    float*    vbuf   = (float*)take((size_t)N_NODES * 256 * 4);
    float*    x1     = (float*)take((size_t)N_NODES * 128 * 4);
    float*    Wc     = (float*)take(2 * 128 * 128 * 4);
    float*    bc     = (float*)take(2 * 128 * 4);
    int*      counts = (int*)take((size_t)N_NODES * 4);
    int*      offs   = (int*)take((size_t)(N_NODES + 1) * 4);
    int*      cursor = (int*)take((size_t)N_NODES * 4);
    int*      csr    = (int*)take((size_t)N_EDGES * 4);
    int*      bsum   = (int*)take((size_t)SCAN_BLOCKS * 4);
    int*      boff   = (int*)take((size_t)SCAN_BLOCKS * 4);
    float*    psum   = (float*)take(NGRAPH * 128 * 4);
    unsigned* pmax   = (unsigned*)take(NGRAPH * 128 * 4);
    int*      pcnt   = (int*)take(NGRAPH * 4);

    const int EB = (N_EDGES + 255) / 256;          // 3125
    const int NB = (N_NODES + 255) / 256;          // 196
    const int TB = (N_NODES + 31) / 32;            // 1563

    // ---- CSR build (shared by both layers) ----
    hipMemsetAsync(counts, 0, (size_t)N_NODES * 4, stream);
    degree_kernel<<<EB, 256, 0, stream>>>(ei, counts);
    block_sum_kernel<<<SCAN_BLOCKS, 256, 0, stream>>>(counts, bsum);
    scan_bsum_kernel<<<1, 256, 0, stream>>>(bsum, boff);
    block_scan_kernel<<<SCAN_BLOCKS, 256, 0, stream>>>(counts, boff, offs, cursor);
    scatter_kernel<<<EB, 256, 0, stream>>>(ei, cursor, csr);

    // ---- skip-path fusion ----
    wc_kernel<<<128, 256, 0, stream>>>(Wsk, Wt, Wc);
    bc_kernel<<<1, 256, 0, stream>>>(bsk, Wt, bt, bc);

    // ---- layer 0 ----
    proj_kernel<<<TB, 256, 0, stream>>>(x, Wq, bq, Wk, bk, Wv, bv, qbuf, kbuf, vbuf);
    attn_kernel<<<N_NODES, 64, 0, stream>>>(qbuf, kbuf, vbuf, offs, csr, qbuf);
    out_linear_kernel<<<TB, 256, 0, stream>>>(qbuf, x, Wt, Wc, bc, x1);

    // ---- layer 1 ----
    proj_kernel<<<TB, 256, 0, stream>>>(x1, Wq + 32768, bq + 256, Wk + 32768, bk + 256,
                                        Wv + 32768, bv + 256, qbuf, kbuf, vbuf);
    attn_kernel<<<N_NODES, 64, 0, stream>>>(qbuf, kbuf, vbuf, offs, csr, qbuf);
    out_linear_kernel<<<TB, 256, 0, stream>>>(qbuf, x1, Wt + 32768, Wc + 16384, bc + 128, x1);

    // ---- pooling ----
    hipMemsetAsync(psum, 0, NGRAPH * 128 * 4, stream);
    hipMemsetAsync(pmax, 0, NGRAPH * 128 * 4, stream);
    hipMemsetAsync(pcnt, 0, NGRAPH * 4, stream);
    pool_count_kernel<<<NB, 256, 0, stream>>>(gi, pcnt);
    pool_accum_kernel<<<(N_NODES * 128 + 255) / 256, 256, 0, stream>>>(x1, gi, psum, pmax);
    pool_final_kernel<<<(NGRAPH * 384 + 255) / 256, 256, 0, stream>>>(psum, pmax, pcnt, out);
}

// Round 3
// 1285.670 us; speedup vs baseline: 1.6040x; 1.3311x over previous
//
#include <hip/hip_runtime.h>
#include <math.h>

#define N_NODES 50000
#define N_EDGES 800000
#define NGRAPH  64
#define CAP_DEG 256
#define SCAN_BLOCKS ((N_NODES + 255) / 256)   // 196

typedef __bf16 bf16x8 __attribute__((ext_vector_type(8)));
typedef float  f32x4  __attribute__((ext_vector_type(4)));

__device__ __forceinline__ unsigned short f2bf(float f) {
    unsigned u = __float_as_uint(f);
    u += 0x7fff + ((u >> 16) & 1);          // round-to-nearest-even
    return (unsigned short)(u >> 16);
}

// ---------------------------------------------------------------------------
// CSR build
// ---------------------------------------------------------------------------
__global__ void degree_kernel(const int* __restrict__ ei, int* __restrict__ counts) {
    int e = blockIdx.x * 256 + threadIdx.x;
    if (e < N_EDGES) atomicAdd(&counts[ei[N_EDGES + e]], 1);
}

__global__ __launch_bounds__(256) void block_sum_kernel(const int* __restrict__ counts,
                                                        int* __restrict__ bsum) {
    int i = blockIdx.x * 256 + threadIdx.x;
    int v = (i < N_NODES) ? counts[i] : 0;
    #pragma unroll
    for (int o = 32; o >= 1; o >>= 1) v += __shfl_xor(v, o);
    __shared__ int ws[4];
    if ((threadIdx.x & 63) == 0) ws[threadIdx.x >> 6] = v;
    __syncthreads();
    if (threadIdx.x == 0) bsum[blockIdx.x] = ws[0] + ws[1] + ws[2] + ws[3];
}

__global__ __launch_bounds__(256) void scan_bsum_kernel(const int* __restrict__ bsum,
                                                        int* __restrict__ boff) {
    int t = threadIdx.x;
    int v = (t < SCAN_BLOCKS) ? bsum[t] : 0;
    int lane = t & 63, wid = t >> 6;
    int incl = v;
    #pragma unroll
    for (int o = 1; o < 64; o <<= 1) {
        int tv = __shfl_up(incl, o);
        if (lane >= o) incl += tv;
    }
    __shared__ int wsum[4];
    if (lane == 63) wsum[wid] = incl;
    __syncthreads();
    int add = 0;
    for (int w = 0; w < wid; w++) add += wsum[w];
    if (t < SCAN_BLOCKS) boff[t] = add + incl - v;   // exclusive
}

__global__ __launch_bounds__(256) void block_scan_kernel(const int* __restrict__ counts,
                                                         const int* __restrict__ boff,
                                                         int* __restrict__ offs,
                                                         int* __restrict__ cursor) {
    int i = blockIdx.x * 256 + threadIdx.x;
    int v = (i < N_NODES) ? counts[i] : 0;
    int lane = threadIdx.x & 63, wid = threadIdx.x >> 6;
    int incl = v;
    #pragma unroll
    for (int o = 1; o < 64; o <<= 1) {
        int tv = __shfl_up(incl, o);
        if (lane >= o) incl += tv;
    }
    __shared__ int wsum[4];
    if (lane == 63) wsum[wid] = incl;
    __syncthreads();
    int add = boff[blockIdx.x];
    for (int w = 0; w < wid; w++) add += wsum[w];
    if (i < N_NODES) {
        offs[i + 1] = add + incl;
        cursor[i]   = add + incl - v;
    }
    if (i == 0) offs[0] = 0;
}

__global__ void scatter_kernel(const int* __restrict__ ei, int* __restrict__ cursor,
                               int* __restrict__ csr) {
    int e = blockIdx.x * 256 + threadIdx.x;
    if (e < N_EDGES) {
        int d = ei[N_EDGES + e];
        int pos = atomicAdd(&cursor[d], 1);
        csr[pos] = ei[e];  // src
    }
}

// ---------------------------------------------------------------------------
// Skip-path fusion (fp32): Wc[l] = Ws[l] @ Wt[l], bc[l] = bs[l] @ Wt[l] + bt[l]
// ---------------------------------------------------------------------------
__global__ void wc_kernel(const float* __restrict__ Ws, const float* __restrict__ Wt,
                          float* __restrict__ Wc) {
    int idx = blockIdx.x * 256 + threadIdx.x;       // 2*128*128 = 32768
    int l = idx >> 14, ij = idx & 16383, i = ij >> 7, j = ij & 127;
    const float* a = Ws + (size_t)l * 32768;
    const float* b = Wt + (size_t)l * 32768;
    float s = 0.f;
    for (int k = 0; k < 256; k++) s = fmaf(a[i * 256 + k], b[k * 128 + j], s);
    Wc[idx] = s;
}

__global__ void bc_kernel(const float* __restrict__ bs, const float* __restrict__ Wt,
                          const float* __restrict__ bt, float* __restrict__ bc) {
    int idx = threadIdx.x;                           // 2 layers x 128
    int l = idx >> 7, j = idx & 127;
    const float* b = Wt + (size_t)l * 32768;
    float s = bt[l * 128 + j];
    for (int k = 0; k < 256; k++) s = fmaf(bs[l * 256 + k], b[k * 128 + j], s);
    bc[idx] = s;
}

// ---------------------------------------------------------------------------
// Weight packing into MFMA B-fragment layout (bf16, ks-major):
//   packed[((ks*CT + ct)*64 + lane)*8 + j] = W[ks*32 + (lane>>4)*8 + j][ct*16 + (lane&15)]
// ---------------------------------------------------------------------------
__global__ void pack_qkv_kernel(const float* __restrict__ Wq, const float* __restrict__ Wk,
                                const float* __restrict__ Wv, unsigned short* __restrict__ out) {
    int idx = blockIdx.x * 256 + threadIdx.x;        // 2*3*32768 = 196608
    if (idx >= 196608) return;
    int j = idx & 7, lane = (idx >> 3) & 63, ct = (idx >> 9) & 15, ks = (idx >> 13) & 3;
    int m3 = idx >> 15;                              // 0..5
    int l = m3 / 3, m = m3 % 3;
    int k = ks * 32 + ((lane >> 4) * 8) + j;
    int n = ct * 16 + (lane & 15);
    const float* W = (m == 0) ? Wq : (m == 1) ? Wk : Wv;
    out[idx] = f2bf(W[(size_t)l * 32768 + k * 256 + n]);
}

// fused [Wt;Wc] (K=384, Ncols=128): KS=12 (ks 0..7 from Wt, 8..11 from Wc), CT=8
__global__ void pack_fused_kernel(const float* __restrict__ Wt, const float* __restrict__ Wc,
                                  unsigned short* __restrict__ out) {
    int idx = blockIdx.x * 256 + threadIdx.x;        // 2*49152 = 98304
    if (idx >= 98304) return;
    int l = idx / 49152, r = idx % 49152;
    int j = r & 7, lane = (r >> 3) & 63;
    int rest = r >> 9;
    int ct = rest & 7, ks = rest >> 3;               // ks 0..11
    int k = ks * 32 + ((lane >> 4) * 8) + j;
    int n = ct * 16 + (lane & 15);
    float v = (k < 256) ? Wt[(size_t)l * 32768 + k * 128 + n]
                        : Wc[(size_t)l * 16384 + (k - 256) * 128 + n];
    out[idx] = f2bf(v);
}

// fp32 -> bf16 elementwise (x input), 4 elems/thread
__global__ void f2bf_kernel(const float* __restrict__ in, unsigned short* __restrict__ out, int n4) {
    int i = blockIdx.x * 256 + threadIdx.x;
    if (i >= n4) return;
    float4 v = ((const float4*)in)[i];
    ushort4 o;
    o.x = f2bf(v.x); o.y = f2bf(v.y); o.z = f2bf(v.z); o.w = f2bf(v.w);
    ((ushort4*)out)[i] = o;
}

// ---------------------------------------------------------------------------
// MFMA q/k/v projection: [N,128]bf16 @ 3x[128,256] -> 3x[N,256]fp32
// block = 256 threads = 4 waves; wave handles 32 rows (two 16-row tiles).
// ---------------------------------------------------------------------------
__global__ __launch_bounds__(256) void proj_mfma_kernel(
    const unsigned short* __restrict__ xb, const unsigned short* __restrict__ Wp,
    const float* __restrict__ b0, const float* __restrict__ b1, const float* __restrict__ b2,
    float* __restrict__ o0, float* __restrict__ o1, float* __restrict__ o2) {
    int w = threadIdx.x >> 6, lane = threadIdx.x & 63;
    int quad = lane >> 4, lr = lane & 15;
    int rbase = blockIdx.x * 128 + w * 32;

    bf16x8 a[2][4];
    #pragma unroll
    for (int s = 0; s < 2; s++) {
        int r = rbase + s * 16 + lr;
        if (r > N_NODES - 1) r = N_NODES - 1;
        const unsigned short* xr = xb + (size_t)r * 128 + quad * 8;
        #pragma unroll
        for (int ks = 0; ks < 4; ks++) a[s][ks] = *(const bf16x8*)(xr + ks * 32);
    }

    const float* bias[3] = {b0, b1, b2};
    float*       outp[3] = {o0, o1, o2};
    for (int mm = 0; mm < 3; mm++) {
        const unsigned short* wp = Wp + mm * 32768;
        for (int ct = 0; ct < 16; ct++) {
            f32x4 c0 = {0.f, 0.f, 0.f, 0.f}, c1 = {0.f, 0.f, 0.f, 0.f};
            #pragma unroll
            for (int ks = 0; ks < 4; ks++) {
                bf16x8 b = *(const bf16x8*)(wp + (size_t)((ks * 16 + ct) * 64 + lane) * 8);
                c0 = __builtin_amdgcn_mfma_f32_16x16x32_bf16(a[0][ks], b, c0, 0, 0, 0);
                c1 = __builtin_amdgcn_mfma_f32_16x16x32_bf16(a[1][ks], b, c1, 0, 0, 0);
            }
            int col = ct * 16 + lr;
            float bb = bias[mm][col];
            float* o = outp[mm];
            #pragma unroll
            for (int r = 0; r < 4; r++) {
                int row0 = rbase + quad * 4 + r;
                if (row0 < N_NODES) o[(size_t)row0 * 256 + col] = c0[r] + bb;
                int row1 = rbase + 16 + quad * 4 + r;
                if (row1 < N_NODES) o[(size_t)row1 * 256 + col] = c1[r] + bb;
            }
        }
    }
}

// ---------------------------------------------------------------------------
// MFMA output linear: x_next = relu([h|x] @ [Wt;Wc] + bc); writes fp32 + bf16
// ---------------------------------------------------------------------------
__global__ __launch_bounds__(256) void out_mfma_kernel(
    const unsigned short* __restrict__ hb, const unsigned short* __restrict__ xb,
    const unsigned short* __restrict__ Wfp, const float* __restrict__ bc,
    float* __restrict__ xout, unsigned short* __restrict__ xbout) {
    int w = threadIdx.x >> 6, lane = threadIdx.x & 63;
    int quad = lane >> 4, lr = lane & 15;
    int rbase = blockIdx.x * 128 + w * 32;
    int r0 = rbase + lr;      if (r0 > N_NODES - 1) r0 = N_NODES - 1;
    int r1 = rbase + 16 + lr; if (r1 > N_NODES - 1) r1 = N_NODES - 1;

    f32x4 acc[8][2];
    #pragma unroll
    for (int ct = 0; ct < 8; ct++) {
        acc[ct][0] = (f32x4){0.f, 0.f, 0.f, 0.f};
        acc[ct][1] = (f32x4){0.f, 0.f, 0.f, 0.f};
    }

    #pragma unroll 4
    for (int ks = 0; ks < 12; ks++) {
        bf16x8 a0, a1;
        if (ks < 8) {
            a0 = *(const bf16x8*)(hb + (size_t)r0 * 256 + ks * 32 + quad * 8);
            a1 = *(const bf16x8*)(hb + (size_t)r1 * 256 + ks * 32 + quad * 8);
        } else {
            a0 = *(const bf16x8*)(xb + (size_t)r0 * 128 + (ks - 8) * 32 + quad * 8);
            a1 = *(const bf16x8*)(xb + (size_t)r1 * 128 + (ks - 8) * 32 + quad * 8);
        }
        #pragma unroll
        for (int ct = 0; ct < 8; ct++) {
            bf16x8 b = *(const bf16x8*)(Wfp + (size_t)((ks * 8 + ct) * 64 + lane) * 8);
            acc[ct][0] = __builtin_amdgcn_mfma_f32_16x16x32_bf16(a0, b, acc[ct][0], 0, 0, 0);
            acc[ct][1] = __builtin_amdgcn_mfma_f32_16x16x32_bf16(a1, b, acc[ct][1], 0, 0, 0);
        }
    }

    #pragma unroll
    for (int ct = 0; ct < 8; ct++) {
        int col = ct * 16 + lr;
        float bb = bc[col];
        #pragma unroll
        for (int r = 0; r < 4; r++) {
            int row0 = rbase + quad * 4 + r;
            if (row0 < N_NODES) {
                float v = fmaxf(acc[ct][0][r] + bb, 0.f);
                xout[(size_t)row0 * 128 + col] = v;
                xbout[(size_t)row0 * 128 + col] = f2bf(v);
            }
            int row1 = rbase + 16 + quad * 4 + r;
            if (row1 < N_NODES) {
                float v = fmaxf(acc[ct][1][r] + bb, 0.f);
                xout[(size_t)row1 * 128 + col] = v;
                xbout[(size_t)row1 * 128 + col] = f2bf(v);
            }
        }
    }
}

// ---------------------------------------------------------------------------
// Attention (fp32 math, bf16 output). One wave per dst node; float4 layout:
// lane i holds row elems [4i,4i+4); head0 = lanes 0..31, head1 = lanes 32..63.
// ---------------------------------------------------------------------------
__global__ __launch_bounds__(64) void attn_kernel(
    const float* __restrict__ q, const float* __restrict__ kk, const float* __restrict__ vv,
    const int* __restrict__ offs, const int* __restrict__ csr,
    unsigned short* __restrict__ hout) {
    __shared__ float slog[2 * CAP_DEG];
    const float SCALE = 0.08838834764831845f;  // 1/sqrt(128)
    int n = blockIdx.x, lane = threadIdx.x;
    float4 q4 = ((const float4*)(q + (size_t)n * 256))[lane];
    int beg = offs[n], end = offs[n + 1], deg = end - beg;
    bool lo = lane < 32;

    float4 acc = make_float4(0.f, 0.f, 0.f, 0.f);
    float d0 = 0.f, d1 = 0.f;
    float m0 = -1e30f, m1 = -1e30f;

    if (deg <= CAP_DEG) {
        int j = 0;
        for (; j + 2 <= deg; j += 2) {
            int s0 = csr[beg + j], s1 = csr[beg + j + 1];
            float4 ka = ((const float4*)(kk + (size_t)s0 * 256))[lane];
            float4 kb = ((const float4*)(kk + (size_t)s1 * 256))[lane];
            float pa = q4.x * ka.x + q4.y * ka.y + q4.z * ka.z + q4.w * ka.w;
            float pb = q4.x * kb.x + q4.y * kb.y + q4.z * kb.z + q4.w * kb.w;
            #pragma unroll
            for (int o = 16; o >= 1; o >>= 1) {
                pa += __shfl_xor(pa, o);
                pb += __shfl_xor(pb, o);
            }
            float xa = __shfl_xor(pa, 32), xb_ = __shfl_xor(pb, 32);
            float la0 = (lo ? pa : xa) * SCALE, la1 = (lo ? xa : pa) * SCALE;
            float lb0 = (lo ? pb : xb_) * SCALE, lb1 = (lo ? xb_ : pb) * SCALE;
            if (lane == 0) {
                slog[2 * j] = la0; slog[2 * j + 1] = la1;
                slog[2 * j + 2] = lb0; slog[2 * j + 3] = lb1;
            }
            m0 = fmaxf(m0, fmaxf(la0, lb0));
            m1 = fmaxf(m1, fmaxf(la1, lb1));
        }
        if (j < deg) {
            int s0 = csr[beg + j];
            float4 ka = ((const float4*)(kk + (size_t)s0 * 256))[lane];
            float pa = q4.x * ka.x + q4.y * ka.y + q4.z * ka.z + q4.w * ka.w;
            #pragma unroll
            for (int o = 16; o >= 1; o >>= 1) pa += __shfl_xor(pa, o);
            float xa = __shfl_xor(pa, 32);
            float la0 = (lo ? pa : xa) * SCALE, la1 = (lo ? xa : pa) * SCALE;
            if (lane == 0) { slog[2 * j] = la0; slog[2 * j + 1] = la1; }
            m0 = fmaxf(m0, la0);
            m1 = fmaxf(m1, la1);
        }
        j = 0;
        for (; j + 2 <= deg; j += 2) {
            float ea0 = __expf(slog[2 * j]     - m0), ea1 = __expf(slog[2 * j + 1] - m1);
            float eb0 = __expf(slog[2 * j + 2] - m0), eb1 = __expf(slog[2 * j + 3] - m1);
            d0 += ea0 + eb0;
            d1 += ea1 + eb1;
            int s0 = csr[beg + j], s1 = csr[beg + j + 1];
            float4 va = ((const float4*)(vv + (size_t)s0 * 256))[lane];
            float4 vb = ((const float4*)(vv + (size_t)s1 * 256))[lane];
            float wa = lo ? ea0 : ea1, wb = lo ? eb0 : eb1;
            acc.x = fmaf(wa, va.x, fmaf(wb, vb.x, acc.x));
            acc.y = fmaf(wa, va.y, fmaf(wb, vb.y, acc.y));
            acc.z = fmaf(wa, va.z, fmaf(wb, vb.z, acc.z));
            acc.w = fmaf(wa, va.w, fmaf(wb, vb.w, acc.w));
        }
        if (j < deg) {
            float ea0 = __expf(slog[2 * j] - m0), ea1 = __expf(slog[2 * j + 1] - m1);
            d0 += ea0;
            d1 += ea1;
            int s0 = csr[beg + j];
            float4 va = ((const float4*)(vv + (size_t)s0 * 256))[lane];
            float wa = lo ? ea0 : ea1;
            acc.x = fmaf(wa, va.x, acc.x);
            acc.y = fmaf(wa, va.y, acc.y);
            acc.z = fmaf(wa, va.z, acc.z);
            acc.w = fmaf(wa, va.w, acc.w);
        }
    } else {
        auto elog = [&](int s, float& l0, float& l1) {
            float4 k4 = ((const float4*)(kk + (size_t)s * 256))[lane];
            float p = q4.x * k4.x + q4.y * k4.y + q4.z * k4.z + q4.w * k4.w;
            #pragma unroll
            for (int o = 16; o >= 1; o >>= 1) p += __shfl_xor(p, o);
            float x = __shfl_xor(p, 32);
            l0 = (lo ? p : x) * SCALE;
            l1 = (lo ? x : p) * SCALE;
        };
        for (int j = 0; j < deg; j++) {
            float l0, l1;
            elog(csr[beg + j], l0, l1);
            m0 = fmaxf(m0, l0);
            m1 = fmaxf(m1, l1);
        }
        for (int j = 0; j < deg; j++) {
            float l0, l1;
            int s = csr[beg + j];
            elog(s, l0, l1);
            float e0 = __expf(l0 - m0), e1 = __expf(l1 - m1);
            d0 += e0;
            d1 += e1;
            float4 va = ((const float4*)(vv + (size_t)s * 256))[lane];
            float w_ = lo ? e0 : e1;
            acc.x = fmaf(w_, va.x, acc.x);
            acc.y = fmaf(w_, va.y, acc.y);
            acc.z = fmaf(w_, va.z, acc.z);
            acc.w = fmaf(w_, va.w, acc.w);
        }
    }
    float inv = lo ? (1.f / (d0 + 1e-16f)) : (1.f / (d1 + 1e-16f));
    ushort4 hv;
    hv.x = f2bf(acc.x * inv);
    hv.y = f2bf(acc.y * inv);
    hv.z = f2bf(acc.z * inv);
    hv.w = f2bf(acc.w * inv);
    ((ushort4*)(hout + (size_t)n * 256))[lane] = hv;
}

// ---------------------------------------------------------------------------
// Pooling: relu output => values >= 0 => uint atomicMax is order-correct
// ---------------------------------------------------------------------------
__global__ void pool_count_kernel(const int* __restrict__ gi, int* __restrict__ pcnt) {
    int i = blockIdx.x * 256 + threadIdx.x;
    if (i < N_NODES) atomicAdd(&pcnt[gi[i]], 1);
}

__global__ void pool_accum_kernel(const float* __restrict__ x, const int* __restrict__ gi,
                                  float* __restrict__ psum, unsigned* __restrict__ pmax) {
    int idx = blockIdx.x * 256 + threadIdx.x;
    if (idx >= N_NODES * 128) return;
    int n = idx >> 7, d = idx & 127;
    int g = gi[n];
    float v = x[idx];
    atomicAdd(&psum[g * 128 + d], v);
    atomicMax(&pmax[g * 128 + d], __float_as_uint(v));
}

__global__ void pool_final_kernel(const float* __restrict__ psum, const unsigned* __restrict__ pmax,
                                  const int* __restrict__ pcnt, float* __restrict__ out) {
    int idx = blockIdx.x * 256 + threadIdx.x;
    if (idx >= NGRAPH * 384) return;
    int g = idx / 384, c = idx % 384;
    float r;
    if (c < 128)       r = __uint_as_float(pmax[g * 128 + c]);
    else if (c < 256)  r = psum[g * 128 + (c - 128)] / fmaxf((float)pcnt[g], 1.f);
    else               r = psum[g * 128 + (c - 256)];
    out[idx] = r;
}

// ---------------------------------------------------------------------------
extern "C" void kernel_launch(void* const* d_in, const int* in_sizes, int n_in,
                              void* d_out, int out_size, void* d_ws, size_t ws_size,
                              hipStream_t stream) {
    const float* x   = (const float*)d_in[0];
    const int*   ei  = (const int*)d_in[1];
    const int*   gi  = (const int*)d_in[2];
    const float* Wq  = (const float*)d_in[3];
    const float* bq  = (const float*)d_in[4];
    const float* Wk  = (const float*)d_in[5];
    const float* bk  = (const float*)d_in[6];
    const float* Wv  = (const float*)d_in[7];
    const float* bv  = (const float*)d_in[8];
    const float* Wsk = (const float*)d_in[9];
    const float* bsk = (const float*)d_in[10];
    const float* Wt  = (const float*)d_in[11];
    const float* bt  = (const float*)d_in[12];
    float* out = (float*)d_out;

    char* p = (char*)d_ws;
    auto take = [&](size_t bytes) -> char* {
        char* r = p;
        p += (bytes + 255) & ~(size_t)255;
        return r;
    };
    float*          qbuf   = (float*)take((size_t)N_NODES * 256 * 4);
    float*          kbuf   = (float*)take((size_t)N_NODES * 256 * 4);
    float*          vbuf   = (float*)take((size_t)N_NODES * 256 * 4);
    float*          x1     = (float*)take((size_t)N_NODES * 128 * 4);
    unsigned short* xb     = (unsigned short*)take((size_t)N_NODES * 128 * 2);  // layer0 A
    unsigned short* xb2    = (unsigned short*)take((size_t)N_NODES * 128 * 2);  // layer1 A
    unsigned short* hb     = (unsigned short*)take((size_t)N_NODES * 256 * 2);  // attn out bf16
    unsigned short* Wqkvp  = (unsigned short*)take((size_t)196608 * 2);         // packed qkv
    unsigned short* Wfp    = (unsigned short*)take((size_t)98304 * 2);          // packed [Wt;Wc]
    float*          Wc     = (float*)take(2 * 128 * 128 * 4);
    float*          bc     = (float*)take(2 * 128 * 4);
    int*            counts = (int*)take((size_t)N_NODES * 4);
    int*            offs   = (int*)take((size_t)(N_NODES + 1) * 4);
    int*            cursor = (int*)take((size_t)N_NODES * 4);
    int*            csr    = (int*)take((size_t)N_EDGES * 4);
    int*            bsum   = (int*)take((size_t)SCAN_BLOCKS * 4);
    int*            boff   = (int*)take((size_t)SCAN_BLOCKS * 4);
    float*          psum   = (float*)take(NGRAPH * 128 * 4);
    unsigned*       pmax   = (unsigned*)take(NGRAPH * 128 * 4);
    int*            pcnt   = (int*)take(NGRAPH * 4);

    const int EB = (N_EDGES + 255) / 256;          // 3125
    const int NB = (N_NODES + 255) / 256;          // 196
    const int GB = (N_NODES + 127) / 128;          // 391  (MFMA GEMM blocks)

    // ---- CSR build ----
    hipMemsetAsync(counts, 0, (size_t)N_NODES * 4, stream);
    degree_kernel<<<EB, 256, 0, stream>>>(ei, counts);
    block_sum_kernel<<<SCAN_BLOCKS, 256, 0, stream>>>(counts, bsum);
    scan_bsum_kernel<<<1, 256, 0, stream>>>(bsum, boff);
    block_scan_kernel<<<SCAN_BLOCKS, 256, 0, stream>>>(counts, boff, offs, cursor);
    scatter_kernel<<<EB, 256, 0, stream>>>(ei, cursor, csr);

    // ---- weight prep ----
    wc_kernel<<<128, 256, 0, stream>>>(Wsk, Wt, Wc);
    bc_kernel<<<1, 256, 0, stream>>>(bsk, Wt, bt, bc);
    pack_qkv_kernel<<<768, 256, 0, stream>>>(Wq, Wk, Wv, Wqkvp);
    pack_fused_kernel<<<384, 256, 0, stream>>>(Wt, Wc, Wfp);
    f2bf_kernel<<<(N_NODES * 32 + 255) / 256, 256, 0, stream>>>(x, xb, N_NODES * 32);

    // ---- layer 0 ----
    proj_mfma_kernel<<<GB, 256, 0, stream>>>(xb, Wqkvp, bq, bk, bv, qbuf, kbuf, vbuf);
    attn_kernel<<<N_NODES, 64, 0, stream>>>(qbuf, kbuf, vbuf, offs, csr, hb);
    out_mfma_kernel<<<GB, 256, 0, stream>>>(hb, xb, Wfp, bc, x1, xb2);

    // ---- layer 1 ----
    proj_mfma_kernel<<<GB, 256, 0, stream>>>(xb2, Wqkvp + 98304, bq + 256, bk + 256, bv + 256,
                                             qbuf, kbuf, vbuf);
    attn_kernel<<<N_NODES, 64, 0, stream>>>(qbuf, kbuf, vbuf, offs, csr, hb);
    out_mfma_kernel<<<GB, 256, 0, stream>>>(hb, xb2, Wfp + 49152, bc + 128, x1, xb);

    // ---- pooling ----
    hipMemsetAsync(psum, 0, NGRAPH * 128 * 4, stream);
    hipMemsetAsync(pmax, 0, NGRAPH * 128 * 4, stream);
    hipMemsetAsync(pcnt, 0, NGRAPH * 4, stream);
    pool_count_kernel<<<NB, 256, 0, stream>>>(gi, pcnt);
    pool_accum_kernel<<<(N_NODES * 128 + 255) / 256, 256, 0, stream>>>(x1, gi, psum, pmax);
    pool_final_kernel<<<(NGRAPH * 384 + 255) / 256, 256, 0, stream>>>(psum, pmax, pcnt, out);
}

// Round 4
// 860.464 us; speedup vs baseline: 2.3966x; 1.4942x over previous
//
#include <hip/hip_runtime.h>
#include <math.h>

#define N_NODES 50000
#define N_EDGES 800000
#define NGRAPH  64
#define CAP_DEG 256
#define SCAN_BLOCKS ((N_NODES + 255) / 256)   // 196

typedef __bf16 bf16x8 __attribute__((ext_vector_type(8)));
typedef float  f32x4  __attribute__((ext_vector_type(4)));

__device__ __forceinline__ unsigned short f2bf(float f) {
    unsigned u = __float_as_uint(f);
    u += 0x7fff + ((u >> 16) & 1);          // round-to-nearest-even
    return (unsigned short)(u >> 16);
}
__device__ __forceinline__ float bf2f(unsigned short u) {
    return __uint_as_float((unsigned)u << 16);
}

// ---------------------------------------------------------------------------
// CSR build
// ---------------------------------------------------------------------------
__global__ void degree_kernel(const int* __restrict__ ei, int* __restrict__ counts) {
    int e = blockIdx.x * 256 + threadIdx.x;
    if (e < N_EDGES) atomicAdd(&counts[ei[N_EDGES + e]], 1);
}

__global__ __launch_bounds__(256) void block_sum_kernel(const int* __restrict__ counts,
                                                        int* __restrict__ bsum) {
    int i = blockIdx.x * 256 + threadIdx.x;
    int v = (i < N_NODES) ? counts[i] : 0;
    #pragma unroll
    for (int o = 32; o >= 1; o >>= 1) v += __shfl_xor(v, o);
    __shared__ int ws[4];
    if ((threadIdx.x & 63) == 0) ws[threadIdx.x >> 6] = v;
    __syncthreads();
    if (threadIdx.x == 0) bsum[blockIdx.x] = ws[0] + ws[1] + ws[2] + ws[3];
}

__global__ __launch_bounds__(256) void scan_bsum_kernel(const int* __restrict__ bsum,
                                                        int* __restrict__ boff) {
    int t = threadIdx.x;
    int v = (t < SCAN_BLOCKS) ? bsum[t] : 0;
    int lane = t & 63, wid = t >> 6;
    int incl = v;
    #pragma unroll
    for (int o = 1; o < 64; o <<= 1) {
        int tv = __shfl_up(incl, o);
        if (lane >= o) incl += tv;
    }
    __shared__ int wsum[4];
    if (lane == 63) wsum[wid] = incl;
    __syncthreads();
    int add = 0;
    for (int w = 0; w < wid; w++) add += wsum[w];
    if (t < SCAN_BLOCKS) boff[t] = add + incl - v;   // exclusive
}

__global__ __launch_bounds__(256) void block_scan_kernel(const int* __restrict__ counts,
                                                         const int* __restrict__ boff,
                                                         int* __restrict__ offs,
                                                         int* __restrict__ cursor) {
    int i = blockIdx.x * 256 + threadIdx.x;
    int v = (i < N_NODES) ? counts[i] : 0;
    int lane = threadIdx.x & 63, wid = threadIdx.x >> 6;
    int incl = v;
    #pragma unroll
    for (int o = 1; o < 64; o <<= 1) {
        int tv = __shfl_up(incl, o);
        if (lane >= o) incl += tv;
    }
    __shared__ int wsum[4];
    if (lane == 63) wsum[wid] = incl;
    __syncthreads();
    int add = boff[blockIdx.x];
    for (int w = 0; w < wid; w++) add += wsum[w];
    if (i < N_NODES) {
        offs[i + 1] = add + incl;
        cursor[i]   = add + incl - v;
    }
    if (i == 0) offs[0] = 0;
}

__global__ void scatter_kernel(const int* __restrict__ ei, int* __restrict__ cursor,
                               int* __restrict__ csr) {
    int e = blockIdx.x * 256 + threadIdx.x;
    if (e < N_EDGES) {
        int d = ei[N_EDGES + e];
        int pos = atomicAdd(&cursor[d], 1);
        csr[pos] = ei[e];  // src
    }
}

// ---------------------------------------------------------------------------
// Skip-path fusion (fp32): Wc[l] = Ws[l] @ Wt[l], bc[l] = bs[l] @ Wt[l] + bt[l]
// ---------------------------------------------------------------------------
__global__ void wc_kernel(const float* __restrict__ Ws, const float* __restrict__ Wt,
                          float* __restrict__ Wc) {
    int idx = blockIdx.x * 256 + threadIdx.x;       // 2*128*128 = 32768
    int l = idx >> 14, ij = idx & 16383, i = ij >> 7, j = ij & 127;
    const float* a = Ws + (size_t)l * 32768;
    const float* b = Wt + (size_t)l * 32768;
    float s = 0.f;
    for (int k = 0; k < 256; k++) s = fmaf(a[i * 256 + k], b[k * 128 + j], s);
    Wc[idx] = s;
}

__global__ void bc_kernel(const float* __restrict__ bs, const float* __restrict__ Wt,
                          const float* __restrict__ bt, float* __restrict__ bc) {
    int idx = threadIdx.x;                           // 2 layers x 128
    int l = idx >> 7, j = idx & 127;
    const float* b = Wt + (size_t)l * 32768;
    float s = bt[l * 128 + j];
    for (int k = 0; k < 256; k++) s = fmaf(bs[l * 256 + k], b[k * 128 + j], s);
    bc[idx] = s;
}

// ---------------------------------------------------------------------------
// Weight packing into MFMA B-fragment layout (bf16, ks-major)
// ---------------------------------------------------------------------------
__global__ void pack_qkv_kernel(const float* __restrict__ Wq, const float* __restrict__ Wk,
                                const float* __restrict__ Wv, unsigned short* __restrict__ out) {
    int idx = blockIdx.x * 256 + threadIdx.x;        // 2*3*32768 = 196608
    if (idx >= 196608) return;
    int j = idx & 7, lane = (idx >> 3) & 63, ct = (idx >> 9) & 15, ks = (idx >> 13) & 3;
    int m3 = idx >> 15;                              // 0..5
    int l = m3 / 3, m = m3 % 3;
    int k = ks * 32 + ((lane >> 4) * 8) + j;
    int n = ct * 16 + (lane & 15);
    const float* W = (m == 0) ? Wq : (m == 1) ? Wk : Wv;
    out[idx] = f2bf(W[(size_t)l * 32768 + k * 256 + n]);
}

// fused [Wt;Wc] (K=384): KS=12 (ks 0..7 from Wt, 8..11 from Wc), CT=8
__global__ void pack_fused_kernel(const float* __restrict__ Wt, const float* __restrict__ Wc,
                                  unsigned short* __restrict__ out) {
    int idx = blockIdx.x * 256 + threadIdx.x;        // 2*49152 = 98304
    if (idx >= 98304) return;
    int l = idx / 49152, r = idx % 49152;
    int j = r & 7, lane = (r >> 3) & 63;
    int rest = r >> 9;
    int ct = rest & 7, ks = rest >> 3;               // ks 0..11
    int k = ks * 32 + ((lane >> 4) * 8) + j;
    int n = ct * 16 + (lane & 15);
    float v = (k < 256) ? Wt[(size_t)l * 32768 + k * 128 + n]
                        : Wc[(size_t)l * 16384 + (k - 256) * 128 + n];
    out[idx] = f2bf(v);
}

// fp32 -> bf16 elementwise (x input), 4 elems/thread
__global__ void f2bf_kernel(const float* __restrict__ in, unsigned short* __restrict__ out, int n4) {
    int i = blockIdx.x * 256 + threadIdx.x;
    if (i >= n4) return;
    float4 v = ((const float4*)in)[i];
    ushort4 o;
    o.x = f2bf(v.x); o.y = f2bf(v.y); o.z = f2bf(v.z); o.w = f2bf(v.w);
    ((ushort4*)out)[i] = o;
}

// ---------------------------------------------------------------------------
// MFMA q/k/v projection: [N,128]bf16 @ 3x[128,256] -> q fp32, k/v bf16
// ---------------------------------------------------------------------------
__global__ __launch_bounds__(256) void proj_mfma_kernel(
    const unsigned short* __restrict__ xb, const unsigned short* __restrict__ Wp,
    const float* __restrict__ b0, const float* __restrict__ b1, const float* __restrict__ b2,
    float* __restrict__ oq, unsigned short* __restrict__ ok, unsigned short* __restrict__ ov) {
    int w = threadIdx.x >> 6, lane = threadIdx.x & 63;
    int quad = lane >> 4, lr = lane & 15;
    int rbase = blockIdx.x * 128 + w * 32;

    bf16x8 a[2][4];
    #pragma unroll
    for (int s = 0; s < 2; s++) {
        int r = rbase + s * 16 + lr;
        if (r > N_NODES - 1) r = N_NODES - 1;
        const unsigned short* xr = xb + (size_t)r * 128 + quad * 8;
        #pragma unroll
        for (int ks = 0; ks < 4; ks++) a[s][ks] = *(const bf16x8*)(xr + ks * 32);
    }

    const float* bias[3] = {b0, b1, b2};
    for (int mm = 0; mm < 3; mm++) {
        const unsigned short* wp = Wp + mm * 32768;
        unsigned short* obf = (mm == 1) ? ok : ov;
        for (int ct = 0; ct < 16; ct++) {
            f32x4 c0 = {0.f, 0.f, 0.f, 0.f}, c1 = {0.f, 0.f, 0.f, 0.f};
            #pragma unroll
            for (int ks = 0; ks < 4; ks++) {
                bf16x8 b = *(const bf16x8*)(wp + (size_t)((ks * 16 + ct) * 64 + lane) * 8);
                c0 = __builtin_amdgcn_mfma_f32_16x16x32_bf16(a[0][ks], b, c0, 0, 0, 0);
                c1 = __builtin_amdgcn_mfma_f32_16x16x32_bf16(a[1][ks], b, c1, 0, 0, 0);
            }
            int col = ct * 16 + lr;
            float bb = bias[mm][col];
            #pragma unroll
            for (int r = 0; r < 4; r++) {
                int row0 = rbase + quad * 4 + r;
                int row1 = rbase + 16 + quad * 4 + r;
                float v0 = c0[r] + bb, v1 = c1[r] + bb;
                if (mm == 0) {
                    if (row0 < N_NODES) oq[(size_t)row0 * 256 + col] = v0;
                    if (row1 < N_NODES) oq[(size_t)row1 * 256 + col] = v1;
                } else {
                    if (row0 < N_NODES) obf[(size_t)row0 * 256 + col] = f2bf(v0);
                    if (row1 < N_NODES) obf[(size_t)row1 * 256 + col] = f2bf(v1);
                }
            }
        }
    }
}

// ---------------------------------------------------------------------------
// MFMA output linear: x_next = relu([h|x] @ [Wt;Wc] + bc); writes bf16 only
// ---------------------------------------------------------------------------
__global__ __launch_bounds__(256) void out_mfma_kernel(
    const unsigned short* __restrict__ hb, const unsigned short* __restrict__ xb,
    const unsigned short* __restrict__ Wfp, const float* __restrict__ bc,
    unsigned short* __restrict__ xbout) {
    int w = threadIdx.x >> 6, lane = threadIdx.x & 63;
    int quad = lane >> 4, lr = lane & 15;
    int rbase = blockIdx.x * 128 + w * 32;
    int r0 = rbase + lr;      if (r0 > N_NODES - 1) r0 = N_NODES - 1;
    int r1 = rbase + 16 + lr; if (r1 > N_NODES - 1) r1 = N_NODES - 1;

    f32x4 acc[8][2];
    #pragma unroll
    for (int ct = 0; ct < 8; ct++) {
        acc[ct][0] = (f32x4){0.f, 0.f, 0.f, 0.f};
        acc[ct][1] = (f32x4){0.f, 0.f, 0.f, 0.f};
    }

    #pragma unroll 4
    for (int ks = 0; ks < 12; ks++) {
        bf16x8 a0, a1;
        if (ks < 8) {
            a0 = *(const bf16x8*)(hb + (size_t)r0 * 256 + ks * 32 + quad * 8);
            a1 = *(const bf16x8*)(hb + (size_t)r1 * 256 + ks * 32 + quad * 8);
        } else {
            a0 = *(const bf16x8*)(xb + (size_t)r0 * 128 + (ks - 8) * 32 + quad * 8);
            a1 = *(const bf16x8*)(xb + (size_t)r1 * 128 + (ks - 8) * 32 + quad * 8);
        }
        #pragma unroll
        for (int ct = 0; ct < 8; ct++) {
            bf16x8 b = *(const bf16x8*)(Wfp + (size_t)((ks * 8 + ct) * 64 + lane) * 8);
            acc[ct][0] = __builtin_amdgcn_mfma_f32_16x16x32_bf16(a0, b, acc[ct][0], 0, 0, 0);
            acc[ct][1] = __builtin_amdgcn_mfma_f32_16x16x32_bf16(a1, b, acc[ct][1], 0, 0, 0);
        }
    }

    #pragma unroll
    for (int ct = 0; ct < 8; ct++) {
        int col = ct * 16 + lr;
        float bb = bc[col];
        #pragma unroll
        for (int r = 0; r < 4; r++) {
            int row0 = rbase + quad * 4 + r;
            if (row0 < N_NODES)
                xbout[(size_t)row0 * 128 + col] = f2bf(fmaxf(acc[ct][0][r] + bb, 0.f));
            int row1 = rbase + 16 + quad * 4 + r;
            if (row1 < N_NODES)
                xbout[(size_t)row1 * 128 + col] = f2bf(fmaxf(acc[ct][1][r] + bb, 0.f));
        }
    }
}

// ---------------------------------------------------------------------------
// Attention: q fp32, k/v bf16 gathers (ushort4 = 8B/lane, 512B/wave/row).
// One wave per dst node; lane i holds row elems [4i,4i+4);
// head0 = lanes 0..31, head1 = lanes 32..63.
// ---------------------------------------------------------------------------
__global__ __launch_bounds__(64) void attn_kernel(
    const float* __restrict__ q, const unsigned short* __restrict__ kk,
    const unsigned short* __restrict__ vv,
    const int* __restrict__ offs, const int* __restrict__ csr,
    unsigned short* __restrict__ hout) {
    __shared__ float slog[2 * CAP_DEG];
    const float SCALE = 0.08838834764831845f;  // 1/sqrt(128)
    int n = blockIdx.x, lane = threadIdx.x;
    float4 q4 = ((const float4*)(q + (size_t)n * 256))[lane];
    int beg = offs[n], end = offs[n + 1], deg = end - beg;
    bool lo = lane < 32;

    float4 acc = make_float4(0.f, 0.f, 0.f, 0.f);
    float d0 = 0.f, d1 = 0.f;
    float m0 = -1e30f, m1 = -1e30f;

    auto ld4 = [&](const unsigned short* base, int s) {
        ushort4 u = ((const ushort4*)(base + (size_t)s * 256))[lane];
        return make_float4(bf2f(u.x), bf2f(u.y), bf2f(u.z), bf2f(u.w));
    };

    if (deg <= CAP_DEG) {
        int j = 0;
        for (; j + 2 <= deg; j += 2) {
            int s0 = csr[beg + j], s1 = csr[beg + j + 1];
            float4 ka = ld4(kk, s0);
            float4 kb = ld4(kk, s1);
            float pa = q4.x * ka.x + q4.y * ka.y + q4.z * ka.z + q4.w * ka.w;
            float pb = q4.x * kb.x + q4.y * kb.y + q4.z * kb.z + q4.w * kb.w;
            #pragma unroll
            for (int o = 16; o >= 1; o >>= 1) {
                pa += __shfl_xor(pa, o);
                pb += __shfl_xor(pb, o);
            }
            float xa = __shfl_xor(pa, 32), xb_ = __shfl_xor(pb, 32);
            float la0 = (lo ? pa : xa) * SCALE, la1 = (lo ? xa : pa) * SCALE;
            float lb0 = (lo ? pb : xb_) * SCALE, lb1 = (lo ? xb_ : pb) * SCALE;
            if (lane == 0) {
                slog[2 * j] = la0; slog[2 * j + 1] = la1;
                slog[2 * j + 2] = lb0; slog[2 * j + 3] = lb1;
            }
            m0 = fmaxf(m0, fmaxf(la0, lb0));
            m1 = fmaxf(m1, fmaxf(la1, lb1));
        }
        if (j < deg) {
            int s0 = csr[beg + j];
            float4 ka = ld4(kk, s0);
            float pa = q4.x * ka.x + q4.y * ka.y + q4.z * ka.z + q4.w * ka.w;
            #pragma unroll
            for (int o = 16; o >= 1; o >>= 1) pa += __shfl_xor(pa, o);
            float xa = __shfl_xor(pa, 32);
            float la0 = (lo ? pa : xa) * SCALE, la1 = (lo ? xa : pa) * SCALE;
            if (lane == 0) { slog[2 * j] = la0; slog[2 * j + 1] = la1; }
            m0 = fmaxf(m0, la0);
            m1 = fmaxf(m1, la1);
        }
        j = 0;
        for (; j + 2 <= deg; j += 2) {
            float ea0 = __expf(slog[2 * j]     - m0), ea1 = __expf(slog[2 * j + 1] - m1);
            float eb0 = __expf(slog[2 * j + 2] - m0), eb1 = __expf(slog[2 * j + 3] - m1);
            d0 += ea0 + eb0;
            d1 += ea1 + eb1;
            int s0 = csr[beg + j], s1 = csr[beg + j + 1];
            float4 va = ld4(vv, s0);
            float4 vb = ld4(vv, s1);
            float wa = lo ? ea0 : ea1, wb = lo ? eb0 : eb1;
            acc.x = fmaf(wa, va.x, fmaf(wb, vb.x, acc.x));
            acc.y = fmaf(wa, va.y, fmaf(wb, vb.y, acc.y));
            acc.z = fmaf(wa, va.z, fmaf(wb, vb.z, acc.z));
            acc.w = fmaf(wa, va.w, fmaf(wb, vb.w, acc.w));
        }
        if (j < deg) {
            float ea0 = __expf(slog[2 * j] - m0), ea1 = __expf(slog[2 * j + 1] - m1);
            d0 += ea0;
            d1 += ea1;
            float4 va = ld4(vv, csr[beg + j]);
            float wa = lo ? ea0 : ea1;
            acc.x = fmaf(wa, va.x, acc.x);
            acc.y = fmaf(wa, va.y, acc.y);
            acc.z = fmaf(wa, va.z, acc.z);
            acc.w = fmaf(wa, va.w, acc.w);
        }
    } else {
        auto elog = [&](int s, float& l0, float& l1) {
            float4 k4 = ld4(kk, s);
            float p = q4.x * k4.x + q4.y * k4.y + q4.z * k4.z + q4.w * k4.w;
            #pragma unroll
            for (int o = 16; o >= 1; o >>= 1) p += __shfl_xor(p, o);
            float x = __shfl_xor(p, 32);
            l0 = (lo ? p : x) * SCALE;
            l1 = (lo ? x : p) * SCALE;
        };
        for (int j = 0; j < deg; j++) {
            float l0, l1;
            elog(csr[beg + j], l0, l1);
            m0 = fmaxf(m0, l0);
            m1 = fmaxf(m1, l1);
        }
        for (int j = 0; j < deg; j++) {
            float l0, l1;
            int s = csr[beg + j];
            elog(s, l0, l1);
            float e0 = __expf(l0 - m0), e1 = __expf(l1 - m1);
            d0 += e0;
            d1 += e1;
            float4 va = ld4(vv, s);
            float w_ = lo ? e0 : e1;
            acc.x = fmaf(w_, va.x, acc.x);
            acc.y = fmaf(w_, va.y, acc.y);
            acc.z = fmaf(w_, va.z, acc.z);
            acc.w = fmaf(w_, va.w, acc.w);
        }
    }
    float inv = lo ? (1.f / (d0 + 1e-16f)) : (1.f / (d1 + 1e-16f));
    ushort4 hv;
    hv.x = f2bf(acc.x * inv);
    hv.y = f2bf(acc.y * inv);
    hv.z = f2bf(acc.z * inv);
    hv.w = f2bf(acc.w * inv);
    ((ushort4*)(hout + (size_t)n * 256))[lane] = hv;
}

// ---------------------------------------------------------------------------
// Pooling from bf16 x. graph_indices is SORTED, so a 32-node block sees few
// distinct graphs: accumulate per-run locally, one atomic per (col, run).
// relu output >= 0 => uint atomicMax is order-correct, and init 0 is the
// identity for max here.
// ---------------------------------------------------------------------------
__global__ void pool_count_kernel(const int* __restrict__ gi, int* __restrict__ pcnt) {
    int i = blockIdx.x * 256 + threadIdx.x;
    if (i < N_NODES) atomicAdd(&pcnt[gi[i]], 1);
}

__global__ __launch_bounds__(256) void pool_accum_kernel(
    const unsigned short* __restrict__ xb, const int* __restrict__ gi,
    float* __restrict__ psum, unsigned* __restrict__ pmax) {
    int n0 = blockIdx.x * 32;
    int col = threadIdx.x & 127, half = threadIdx.x >> 7;
    float sum = 0.f, mx = 0.f;
    int first = n0 + half;
    if (first >= N_NODES) return;
    int cur_g = gi[first];
    for (int r = half; r < 32; r += 2) {
        int n = n0 + r;
        if (n >= N_NODES) break;
        int g = gi[n];
        if (g != cur_g) {
            atomicAdd(&psum[cur_g * 128 + col], sum);
            atomicMax(&pmax[cur_g * 128 + col], __float_as_uint(mx));
            sum = 0.f; mx = 0.f; cur_g = g;
        }
        float v = bf2f(xb[(size_t)n * 128 + col]);
        sum += v;
        mx = fmaxf(mx, v);
    }
    atomicAdd(&psum[cur_g * 128 + col], sum);
    atomicMax(&pmax[cur_g * 128 + col], __float_as_uint(mx));
}

__global__ void pool_final_kernel(const float* __restrict__ psum, const unsigned* __restrict__ pmax,
                                  const int* __restrict__ pcnt, float* __restrict__ out) {
    int idx = blockIdx.x * 256 + threadIdx.x;
    if (idx >= NGRAPH * 384) return;
    int g = idx / 384, c = idx % 384;
    float r;
    if (c < 128)       r = __uint_as_float(pmax[g * 128 + c]);
    else if (c < 256)  r = psum[g * 128 + (c - 128)] / fmaxf((float)pcnt[g], 1.f);
    else               r = psum[g * 128 + (c - 256)];
    out[idx] = r;
}

// ---------------------------------------------------------------------------
extern "C" void kernel_launch(void* const* d_in, const int* in_sizes, int n_in,
                              void* d_out, int out_size, void* d_ws, size_t ws_size,
                              hipStream_t stream) {
    const float* x   = (const float*)d_in[0];
    const int*   ei  = (const int*)d_in[1];
    const int*   gi  = (const int*)d_in[2];
    const float* Wq  = (const float*)d_in[3];
    const float* bq  = (const float*)d_in[4];
    const float* Wk  = (const float*)d_in[5];
    const float* bk  = (const float*)d_in[6];
    const float* Wv  = (const float*)d_in[7];
    const float* bv  = (const float*)d_in[8];
    const float* Wsk = (const float*)d_in[9];
    const float* bsk = (const float*)d_in[10];
    const float* Wt  = (const float*)d_in[11];
    const float* bt  = (const float*)d_in[12];
    float* out = (float*)d_out;

    char* p = (char*)d_ws;
    auto take = [&](size_t bytes) -> char* {
        char* r = p;
        p += (bytes + 255) & ~(size_t)255;
        return r;
    };
    float*          qbuf   = (float*)take((size_t)N_NODES * 256 * 4);
    unsigned short* kbuf   = (unsigned short*)take((size_t)N_NODES * 256 * 2);
    unsigned short* vbuf   = (unsigned short*)take((size_t)N_NODES * 256 * 2);
    unsigned short* xb     = (unsigned short*)take((size_t)N_NODES * 128 * 2);  // layer0 A / final x
    unsigned short* xb2    = (unsigned short*)take((size_t)N_NODES * 128 * 2);  // layer1 A
    unsigned short* hb     = (unsigned short*)take((size_t)N_NODES * 256 * 2);  // attn out bf16
    unsigned short* Wqkvp  = (unsigned short*)take((size_t)196608 * 2);         // packed qkv
    unsigned short* Wfp    = (unsigned short*)take((size_t)98304 * 2);          // packed [Wt;Wc]
    float*          Wc     = (float*)take(2 * 128 * 128 * 4);
    float*          bc     = (float*)take(2 * 128 * 4);
    int*            counts = (int*)take((size_t)N_NODES * 4);
    int*            offs   = (int*)take((size_t)(N_NODES + 1) * 4);
    int*            cursor = (int*)take((size_t)N_NODES * 4);
    int*            csr    = (int*)take((size_t)N_EDGES * 4);
    int*            bsum   = (int*)take((size_t)SCAN_BLOCKS * 4);
    int*            boff   = (int*)take((size_t)SCAN_BLOCKS * 4);
    float*          psum   = (float*)take(NGRAPH * 128 * 4);
    unsigned*       pmax   = (unsigned*)take(NGRAPH * 128 * 4);
    int*            pcnt   = (int*)take(NGRAPH * 4);

    const int EB = (N_EDGES + 255) / 256;          // 3125
    const int NB = (N_NODES + 255) / 256;          // 196
    const int GB = (N_NODES + 127) / 128;          // 391  (MFMA GEMM blocks)
    const int PB = (N_NODES + 31) / 32;            // 1563 (pooling blocks)

    // ---- CSR build ----
    hipMemsetAsync(counts, 0, (size_t)N_NODES * 4, stream);
    degree_kernel<<<EB, 256, 0, stream>>>(ei, counts);
    block_sum_kernel<<<SCAN_BLOCKS, 256, 0, stream>>>(counts, bsum);
    scan_bsum_kernel<<<1, 256, 0, stream>>>(bsum, boff);
    block_scan_kernel<<<SCAN_BLOCKS, 256, 0, stream>>>(counts, boff, offs, cursor);
    scatter_kernel<<<EB, 256, 0, stream>>>(ei, cursor, csr);

    // ---- weight prep ----
    wc_kernel<<<128, 256, 0, stream>>>(Wsk, Wt, Wc);
    bc_kernel<<<1, 256, 0, stream>>>(bsk, Wt, bt, bc);
    pack_qkv_kernel<<<768, 256, 0, stream>>>(Wq, Wk, Wv, Wqkvp);
    pack_fused_kernel<<<384, 256, 0, stream>>>(Wt, Wc, Wfp);
    f2bf_kernel<<<(N_NODES * 32 + 255) / 256, 256, 0, stream>>>(x, xb, N_NODES * 32);

    // ---- layer 0 ----
    proj_mfma_kernel<<<GB, 256, 0, stream>>>(xb, Wqkvp, bq, bk, bv, qbuf, kbuf, vbuf);
    attn_kernel<<<N_NODES, 64, 0, stream>>>(qbuf, kbuf, vbuf, offs, csr, hb);
    out_mfma_kernel<<<GB, 256, 0, stream>>>(hb, xb, Wfp, bc, xb2);

    // ---- layer 1 ----
    proj_mfma_kernel<<<GB, 256, 0, stream>>>(xb2, Wqkvp + 98304, bq + 256, bk + 256, bv + 256,
                                             qbuf, kbuf, vbuf);
    attn_kernel<<<N_NODES, 64, 0, stream>>>(qbuf, kbuf, vbuf, offs, csr, hb);
    out_mfma_kernel<<<GB, 256, 0, stream>>>(hb, xb2, Wfp + 49152, bc + 128, xb);

    // ---- pooling (reads bf16 x, fp32 accumulate) ----
    hipMemsetAsync(psum, 0, NGRAPH * 128 * 4, stream);
    hipMemsetAsync(pmax, 0, NGRAPH * 128 * 4, stream);
    hipMemsetAsync(pcnt, 0, NGRAPH * 4, stream);
    pool_count_kernel<<<NB, 256, 0, stream>>>(gi, pcnt);
    pool_accum_kernel<<<PB, 256, 0, stream>>>(xb, gi, psum, pmax);
    pool_final_kernel<<<(NGRAPH * 384 + 255) / 256, 256, 0, stream>>>(psum, pmax, pcnt, out);
}

// Round 5
// 638.435 us; speedup vs baseline: 3.2301x; 1.3478x over previous
//
#include <hip/hip_runtime.h>
#include <math.h>

#define N_NODES 50000
#define N_EDGES 800000
#define NGRAPH  64
#define CAP_DEG 256
#define SCAN_BLOCKS ((N_NODES + 255) / 256)   // 196

typedef __bf16 bf16x8 __attribute__((ext_vector_type(8)));
typedef float  f32x4  __attribute__((ext_vector_type(4)));

__device__ __forceinline__ unsigned short f2bf(float f) {
    unsigned u = __float_as_uint(f);
    u += 0x7fff + ((u >> 16) & 1);          // round-to-nearest-even
    return (unsigned short)(u >> 16);
}
__device__ __forceinline__ float bf2f(unsigned short u) {
    return __uint_as_float((unsigned)u << 16);
}

// ---------------------------------------------------------------------------
// CSR build
// ---------------------------------------------------------------------------
__global__ void degree_kernel(const int* __restrict__ ei, int* __restrict__ counts) {
    int e = blockIdx.x * 256 + threadIdx.x;
    if (e < N_EDGES) atomicAdd(&counts[ei[N_EDGES + e]], 1);
}

__global__ __launch_bounds__(256) void block_sum_kernel(const int* __restrict__ counts,
                                                        int* __restrict__ bsum) {
    int i = blockIdx.x * 256 + threadIdx.x;
    int v = (i < N_NODES) ? counts[i] : 0;
    #pragma unroll
    for (int o = 32; o >= 1; o >>= 1) v += __shfl_xor(v, o);
    __shared__ int ws[4];
    if ((threadIdx.x & 63) == 0) ws[threadIdx.x >> 6] = v;
    __syncthreads();
    if (threadIdx.x == 0) bsum[blockIdx.x] = ws[0] + ws[1] + ws[2] + ws[3];
}

__global__ __launch_bounds__(256) void scan_bsum_kernel(const int* __restrict__ bsum,
                                                        int* __restrict__ boff) {
    int t = threadIdx.x;
    int v = (t < SCAN_BLOCKS) ? bsum[t] : 0;
    int lane = t & 63, wid = t >> 6;
    int incl = v;
    #pragma unroll
    for (int o = 1; o < 64; o <<= 1) {
        int tv = __shfl_up(incl, o);
        if (lane >= o) incl += tv;
    }
    __shared__ int wsum[4];
    if (lane == 63) wsum[wid] = incl;
    __syncthreads();
    int add = 0;
    for (int w = 0; w < wid; w++) add += wsum[w];
    if (t < SCAN_BLOCKS) boff[t] = add + incl - v;   // exclusive
}

__global__ __launch_bounds__(256) void block_scan_kernel(const int* __restrict__ counts,
                                                         const int* __restrict__ boff,
                                                         int* __restrict__ offs,
                                                         int* __restrict__ cursor) {
    int i = blockIdx.x * 256 + threadIdx.x;
    int v = (i < N_NODES) ? counts[i] : 0;
    int lane = threadIdx.x & 63, wid = threadIdx.x >> 6;
    int incl = v;
    #pragma unroll
    for (int o = 1; o < 64; o <<= 1) {
        int tv = __shfl_up(incl, o);
        if (lane >= o) incl += tv;
    }
    __shared__ int wsum[4];
    if (lane == 63) wsum[wid] = incl;
    __syncthreads();
    int add = boff[blockIdx.x];
    for (int w = 0; w < wid; w++) add += wsum[w];
    if (i < N_NODES) {
        offs[i + 1] = add + incl;
        cursor[i]   = add + incl - v;
    }
    if (i == 0) offs[0] = 0;
}

__global__ void scatter_kernel(const int* __restrict__ ei, int* __restrict__ cursor,
                               int* __restrict__ csr) {
    int e = blockIdx.x * 256 + threadIdx.x;
    if (e < N_EDGES) {
        int d = ei[N_EDGES + e];
        int pos = atomicAdd(&cursor[d], 1);
        csr[pos] = ei[e];  // src
    }
}

// ---------------------------------------------------------------------------
// Skip-path fusion (fp32): Wc[l] = Ws[l] @ Wt[l], bc[l] = bs[l] @ Wt[l] + bt[l]
// ---------------------------------------------------------------------------
__global__ void wc_kernel(const float* __restrict__ Ws, const float* __restrict__ Wt,
                          float* __restrict__ Wc) {
    int idx = blockIdx.x * 256 + threadIdx.x;       // 2*128*128 = 32768
    int l = idx >> 14, ij = idx & 16383, i = ij >> 7, j = ij & 127;
    const float* a = Ws + (size_t)l * 32768;
    const float* b = Wt + (size_t)l * 32768;
    float s = 0.f;
    for (int k = 0; k < 256; k++) s = fmaf(a[i * 256 + k], b[k * 128 + j], s);
    Wc[idx] = s;
}

__global__ void bc_kernel(const float* __restrict__ bs, const float* __restrict__ Wt,
                          const float* __restrict__ bt, float* __restrict__ bc) {
    int idx = threadIdx.x;                           // 2 layers x 128
    int l = idx >> 7, j = idx & 127;
    const float* b = Wt + (size_t)l * 32768;
    float s = bt[l * 128 + j];
    for (int k = 0; k < 256; k++) s = fmaf(bs[l * 256 + k], b[k * 128 + j], s);
    bc[idx] = s;
}

// ---------------------------------------------------------------------------
// Weight packing into MFMA B-fragment layout (bf16, ks-major)
// ---------------------------------------------------------------------------
__global__ void pack_qkv_kernel(const float* __restrict__ Wq, const float* __restrict__ Wk,
                                const float* __restrict__ Wv, unsigned short* __restrict__ out) {
    int idx = blockIdx.x * 256 + threadIdx.x;        // 2*3*32768 = 196608
    if (idx >= 196608) return;
    int j = idx & 7, lane = (idx >> 3) & 63, ct = (idx >> 9) & 15, ks = (idx >> 13) & 3;
    int m3 = idx >> 15;                              // 0..5
    int l = m3 / 3, m = m3 % 3;
    int k = ks * 32 + ((lane >> 4) * 8) + j;
    int n = ct * 16 + (lane & 15);
    const float* W = (m == 0) ? Wq : (m == 1) ? Wk : Wv;
    out[idx] = f2bf(W[(size_t)l * 32768 + k * 256 + n]);
}

// fused [Wt;Wc] (K=384): KS=12 (ks 0..7 from Wt, 8..11 from Wc), CT=8
__global__ void pack_fused_kernel(const float* __restrict__ Wt, const float* __restrict__ Wc,
                                  unsigned short* __restrict__ out) {
    int idx = blockIdx.x * 256 + threadIdx.x;        // 2*49152 = 98304
    if (idx >= 98304) return;
    int l = idx / 49152, r = idx % 49152;
    int j = r & 7, lane = (r >> 3) & 63;
    int rest = r >> 9;
    int ct = rest & 7, ks = rest >> 3;               // ks 0..11
    int k = ks * 32 + ((lane >> 4) * 8) + j;
    int n = ct * 16 + (lane & 15);
    float v = (k < 256) ? Wt[(size_t)l * 32768 + k * 128 + n]
                        : Wc[(size_t)l * 16384 + (k - 256) * 128 + n];
    out[idx] = f2bf(v);
}

// fp32 -> bf16 elementwise (x input), 4 elems/thread
__global__ void f2bf_kernel(const float* __restrict__ in, unsigned short* __restrict__ out, int n4) {
    int i = blockIdx.x * 256 + threadIdx.x;
    if (i >= n4) return;
    float4 v = ((const float4*)in)[i];
    ushort4 o;
    o.x = f2bf(v.x); o.y = f2bf(v.y); o.z = f2bf(v.z); o.w = f2bf(v.w);
    ((ushort4*)out)[i] = o;
}

// ---------------------------------------------------------------------------
// MFMA q/k/v projection: [N,128]bf16 @ 3x[128,256] -> q fp32, k/v bf16
// ---------------------------------------------------------------------------
__global__ __launch_bounds__(256) void proj_mfma_kernel(
    const unsigned short* __restrict__ xb, const unsigned short* __restrict__ Wp,
    const float* __restrict__ b0, const float* __restrict__ b1, const float* __restrict__ b2,
    float* __restrict__ oq, unsigned short* __restrict__ ok, unsigned short* __restrict__ ov) {
    int w = threadIdx.x >> 6, lane = threadIdx.x & 63;
    int quad = lane >> 4, lr = lane & 15;
    int rbase = blockIdx.x * 128 + w * 32;

    bf16x8 a[2][4];
    #pragma unroll
    for (int s = 0; s < 2; s++) {
        int r = rbase + s * 16 + lr;
        if (r > N_NODES - 1) r = N_NODES - 1;
        const unsigned short* xr = xb + (size_t)r * 128 + quad * 8;
        #pragma unroll
        for (int ks = 0; ks < 4; ks++) a[s][ks] = *(const bf16x8*)(xr + ks * 32);
    }

    const float* bias[3] = {b0, b1, b2};
    for (int mm = 0; mm < 3; mm++) {
        const unsigned short* wp = Wp + mm * 32768;
        unsigned short* obf = (mm == 1) ? ok : ov;
        for (int ct = 0; ct < 16; ct++) {
            f32x4 c0 = {0.f, 0.f, 0.f, 0.f}, c1 = {0.f, 0.f, 0.f, 0.f};
            #pragma unroll
            for (int ks = 0; ks < 4; ks++) {
                bf16x8 b = *(const bf16x8*)(wp + (size_t)((ks * 16 + ct) * 64 + lane) * 8);
                c0 = __builtin_amdgcn_mfma_f32_16x16x32_bf16(a[0][ks], b, c0, 0, 0, 0);
                c1 = __builtin_amdgcn_mfma_f32_16x16x32_bf16(a[1][ks], b, c1, 0, 0, 0);
            }
            int col = ct * 16 + lr;
            float bb = bias[mm][col];
            #pragma unroll
            for (int r = 0; r < 4; r++) {
                int row0 = rbase + quad * 4 + r;
                int row1 = rbase + 16 + quad * 4 + r;
                float v0 = c0[r] + bb, v1 = c1[r] + bb;
                if (mm == 0) {
                    if (row0 < N_NODES) oq[(size_t)row0 * 256 + col] = v0;
                    if (row1 < N_NODES) oq[(size_t)row1 * 256 + col] = v1;
                } else {
                    if (row0 < N_NODES) obf[(size_t)row0 * 256 + col] = f2bf(v0);
                    if (row1 < N_NODES) obf[(size_t)row1 * 256 + col] = f2bf(v1);
                }
            }
        }
    }
}

// ---------------------------------------------------------------------------
// MFMA output linear: x_next = relu([h|x] @ [Wt;Wc] + bc); writes bf16 only
// ---------------------------------------------------------------------------
__global__ __launch_bounds__(256) void out_mfma_kernel(
    const unsigned short* __restrict__ hb, const unsigned short* __restrict__ xb,
    const unsigned short* __restrict__ Wfp, const float* __restrict__ bc,
    unsigned short* __restrict__ xbout) {
    int w = threadIdx.x >> 6, lane = threadIdx.x & 63;
    int quad = lane >> 4, lr = lane & 15;
    int rbase = blockIdx.x * 128 + w * 32;
    int r0 = rbase + lr;      if (r0 > N_NODES - 1) r0 = N_NODES - 1;
    int r1 = rbase + 16 + lr; if (r1 > N_NODES - 1) r1 = N_NODES - 1;

    f32x4 acc[8][2];
    #pragma unroll
    for (int ct = 0; ct < 8; ct++) {
        acc[ct][0] = (f32x4){0.f, 0.f, 0.f, 0.f};
        acc[ct][1] = (f32x4){0.f, 0.f, 0.f, 0.f};
    }

    #pragma unroll 4
    for (int ks = 0; ks < 12; ks++) {
        bf16x8 a0, a1;
        if (ks < 8) {
            a0 = *(const bf16x8*)(hb + (size_t)r0 * 256 + ks * 32 + quad * 8);
            a1 = *(const bf16x8*)(hb + (size_t)r1 * 256 + ks * 32 + quad * 8);
        } else {
            a0 = *(const bf16x8*)(xb + (size_t)r0 * 128 + (ks - 8) * 32 + quad * 8);
            a1 = *(const bf16x8*)(xb + (size_t)r1 * 128 + (ks - 8) * 32 + quad * 8);
        }
        #pragma unroll
        for (int ct = 0; ct < 8; ct++) {
            bf16x8 b = *(const bf16x8*)(Wfp + (size_t)((ks * 8 + ct) * 64 + lane) * 8);
            acc[ct][0] = __builtin_amdgcn_mfma_f32_16x16x32_bf16(a0, b, acc[ct][0], 0, 0, 0);
            acc[ct][1] = __builtin_amdgcn_mfma_f32_16x16x32_bf16(a1, b, acc[ct][1], 0, 0, 0);
        }
    }

    #pragma unroll
    for (int ct = 0; ct < 8; ct++) {
        int col = ct * 16 + lr;
        float bb = bc[col];
        #pragma unroll
        for (int r = 0; r < 4; r++) {
            int row0 = rbase + quad * 4 + r;
            if (row0 < N_NODES)
                xbout[(size_t)row0 * 128 + col] = f2bf(fmaxf(acc[ct][0][r] + bb, 0.f));
            int row1 = rbase + 16 + quad * 4 + r;
            if (row1 < N_NODES)
                xbout[(size_t)row1 * 128 + col] = f2bf(fmaxf(acc[ct][1][r] + bb, 0.f));
        }
    }
}

// ---------------------------------------------------------------------------
// Attention: q fp32, k/v bf16 gathers (ushort4 = 8B/lane, 512B/wave/row).
// One wave per dst node; lane i holds row elems [4i,4i+4);
// head0 = lanes 0..31, head1 = lanes 32..63.
// ---------------------------------------------------------------------------
__global__ __launch_bounds__(64) void attn_kernel(
    const float* __restrict__ q, const unsigned short* __restrict__ kk,
    const unsigned short* __restrict__ vv,
    const int* __restrict__ offs, const int* __restrict__ csr,
    unsigned short* __restrict__ hout) {
    __shared__ float slog[2 * CAP_DEG];
    const float SCALE = 0.08838834764831845f;  // 1/sqrt(128)
    int n = blockIdx.x, lane = threadIdx.x;
    float4 q4 = ((const float4*)(q + (size_t)n * 256))[lane];
    int beg = offs[n], end = offs[n + 1], deg = end - beg;
    bool lo = lane < 32;

    float4 acc = make_float4(0.f, 0.f, 0.f, 0.f);
    float d0 = 0.f, d1 = 0.f;
    float m0 = -1e30f, m1 = -1e30f;

    auto ld4 = [&](const unsigned short* base, int s) {
        ushort4 u = ((const ushort4*)(base + (size_t)s * 256))[lane];
        return make_float4(bf2f(u.x), bf2f(u.y), bf2f(u.z), bf2f(u.w));
    };

    if (deg <= CAP_DEG) {
        int j = 0;
        for (; j + 2 <= deg; j += 2) {
            int s0 = csr[beg + j], s1 = csr[beg + j + 1];
            float4 ka = ld4(kk, s0);
            float4 kb = ld4(kk, s1);
            float pa = q4.x * ka.x + q4.y * ka.y + q4.z * ka.z + q4.w * ka.w;
            float pb = q4.x * kb.x + q4.y * kb.y + q4.z * kb.z + q4.w * kb.w;
            #pragma unroll
            for (int o = 16; o >= 1; o >>= 1) {
                pa += __shfl_xor(pa, o);
                pb += __shfl_xor(pb, o);
            }
            float xa = __shfl_xor(pa, 32), xb_ = __shfl_xor(pb, 32);
            float la0 = (lo ? pa : xa) * SCALE, la1 = (lo ? xa : pa) * SCALE;
            float lb0 = (lo ? pb : xb_) * SCALE, lb1 = (lo ? xb_ : pb) * SCALE;
            if (lane == 0) {
                slog[2 * j] = la0; slog[2 * j + 1] = la1;
                slog[2 * j + 2] = lb0; slog[2 * j + 3] = lb1;
            }
            m0 = fmaxf(m0, fmaxf(la0, lb0));
            m1 = fmaxf(m1, fmaxf(la1, lb1));
        }
        if (j < deg) {
            int s0 = csr[beg + j];
            float4 ka = ld4(kk, s0);
            float pa = q4.x * ka.x + q4.y * ka.y + q4.z * ka.z + q4.w * ka.w;
            #pragma unroll
            for (int o = 16; o >= 1; o >>= 1) pa += __shfl_xor(pa, o);
            float xa = __shfl_xor(pa, 32);
            float la0 = (lo ? pa : xa) * SCALE, la1 = (lo ? xa : pa) * SCALE;
            if (lane == 0) { slog[2 * j] = la0; slog[2 * j + 1] = la1; }
            m0 = fmaxf(m0, la0);
            m1 = fmaxf(m1, la1);
        }
        j = 0;
        for (; j + 2 <= deg; j += 2) {
            float ea0 = __expf(slog[2 * j]     - m0), ea1 = __expf(slog[2 * j + 1] - m1);
            float eb0 = __expf(slog[2 * j + 2] - m0), eb1 = __expf(slog[2 * j + 3] - m1);
            d0 += ea0 + eb0;
            d1 += ea1 + eb1;
            int s0 = csr[beg + j], s1 = csr[beg + j + 1];
            float4 va = ld4(vv, s0);
            float4 vb = ld4(vv, s1);
            float wa = lo ? ea0 : ea1, wb = lo ? eb0 : eb1;
            acc.x = fmaf(wa, va.x, fmaf(wb, vb.x, acc.x));
            acc.y = fmaf(wa, va.y, fmaf(wb, vb.y, acc.y));
            acc.z = fmaf(wa, va.z, fmaf(wb, vb.z, acc.z));
            acc.w = fmaf(wa, va.w, fmaf(wb, vb.w, acc.w));
        }
        if (j < deg) {
            float ea0 = __expf(slog[2 * j] - m0), ea1 = __expf(slog[2 * j + 1] - m1);
            d0 += ea0;
            d1 += ea1;
            float4 va = ld4(vv, csr[beg + j]);
            float wa = lo ? ea0 : ea1;
            acc.x = fmaf(wa, va.x, acc.x);
            acc.y = fmaf(wa, va.y, acc.y);
            acc.z = fmaf(wa, va.z, acc.z);
            acc.w = fmaf(wa, va.w, acc.w);
        }
    } else {
        auto elog = [&](int s, float& l0, float& l1) {
            float4 k4 = ld4(kk, s);
            float p = q4.x * k4.x + q4.y * k4.y + q4.z * k4.z + q4.w * k4.w;
            #pragma unroll
            for (int o = 16; o >= 1; o >>= 1) p += __shfl_xor(p, o);
            float x = __shfl_xor(p, 32);
            l0 = (lo ? p : x) * SCALE;
            l1 = (lo ? x : p) * SCALE;
        };
        for (int j = 0; j < deg; j++) {
            float l0, l1;
            elog(csr[beg + j], l0, l1);
            m0 = fmaxf(m0, l0);
            m1 = fmaxf(m1, l1);
        }
        for (int j = 0; j < deg; j++) {
            float l0, l1;
            int s = csr[beg + j];
            elog(s, l0, l1);
            float e0 = __expf(l0 - m0), e1 = __expf(l1 - m1);
            d0 += e0;
            d1 += e1;
            float4 va = ld4(vv, s);
            float w_ = lo ? e0 : e1;
            acc.x = fmaf(w_, va.x, acc.x);
            acc.y = fmaf(w_, va.y, acc.y);
            acc.z = fmaf(w_, va.z, acc.z);
            acc.w = fmaf(w_, va.w, acc.w);
        }
    }
    float inv = lo ? (1.f / (d0 + 1e-16f)) : (1.f / (d1 + 1e-16f));
    ushort4 hv;
    hv.x = f2bf(acc.x * inv);
    hv.y = f2bf(acc.y * inv);
    hv.z = f2bf(acc.z * inv);
    hv.w = f2bf(acc.w * inv);
    ((ushort4*)(hout + (size_t)n * 256))[lane] = hv;
}

// ---------------------------------------------------------------------------
// Per-graph node counts via binary search over the SORTED graph_indices.
// Replaces 50000 contended atomics with 64 threads x 2 binary searches.
// ---------------------------------------------------------------------------
__global__ __launch_bounds__(64) void graph_count_kernel(const int* __restrict__ gi,
                                                         int* __restrict__ pcnt) {
    int g = threadIdx.x;   // 0..63
    auto lb = [&](int target) {
        int lo = 0, hi = N_NODES;
        while (lo < hi) {
            int mid = (lo + hi) >> 1;
            if (gi[mid] < target) lo = mid + 1;
            else hi = mid;
        }
        return lo;
    };
    int a = lb(g), b = lb(g + 1);
    pcnt[g] = b - a;
}

// ---------------------------------------------------------------------------
// Pooling from bf16 x. gi sorted -> per-run local accumulate, one atomic per
// (col, run). relu output >= 0 => uint atomicMax order-correct, 0 is identity.
// ---------------------------------------------------------------------------
__global__ __launch_bounds__(256) void pool_accum_kernel(
    const unsigned short* __restrict__ xb, const int* __restrict__ gi,
    float* __restrict__ psum, unsigned* __restrict__ pmax) {
    int n0 = blockIdx.x * 32;
    int col = threadIdx.x & 127, half = threadIdx.x >> 7;
    float sum = 0.f, mx = 0.f;
    int first = n0 + half;
    if (first >= N_NODES) return;
    int cur_g = gi[first];
    for (int r = half; r < 32; r += 2) {
        int n = n0 + r;
        if (n >= N_NODES) break;
        int g = gi[n];
        if (g != cur_g) {
            atomicAdd(&psum[cur_g * 128 + col], sum);
            atomicMax(&pmax[cur_g * 128 + col], __float_as_uint(mx));
            sum = 0.f; mx = 0.f; cur_g = g;
        }
        float v = bf2f(xb[(size_t)n * 128 + col]);
        sum += v;
        mx = fmaxf(mx, v);
    }
    atomicAdd(&psum[cur_g * 128 + col], sum);
    atomicMax(&pmax[cur_g * 128 + col], __float_as_uint(mx));
}

__global__ void pool_final_kernel(const float* __restrict__ psum, const unsigned* __restrict__ pmax,
                                  const int* __restrict__ pcnt, float* __restrict__ out) {
    int idx = blockIdx.x * 256 + threadIdx.x;
    if (idx >= NGRAPH * 384) return;
    int g = idx / 384, c = idx % 384;
    float r;
    if (c < 128)       r = __uint_as_float(pmax[g * 128 + c]);
    else if (c < 256)  r = psum[g * 128 + (c - 128)] / fmaxf((float)pcnt[g], 1.f);
    else               r = psum[g * 128 + (c - 256)];
    out[idx] = r;
}

// ---------------------------------------------------------------------------
extern "C" void kernel_launch(void* const* d_in, const int* in_sizes, int n_in,
                              void* d_out, int out_size, void* d_ws, size_t ws_size,
                              hipStream_t stream) {
    const float* x   = (const float*)d_in[0];
    const int*   ei  = (const int*)d_in[1];
    const int*   gi  = (const int*)d_in[2];
    const float* Wq  = (const float*)d_in[3];
    const float* bq  = (const float*)d_in[4];
    const float* Wk  = (const float*)d_in[5];
    const float* bk  = (const float*)d_in[6];
    const float* Wv  = (const float*)d_in[7];
    const float* bv  = (const float*)d_in[8];
    const float* Wsk = (const float*)d_in[9];
    const float* bsk = (const float*)d_in[10];
    const float* Wt  = (const float*)d_in[11];
    const float* bt  = (const float*)d_in[12];
    float* out = (float*)d_out;

    char* p = (char*)d_ws;
    auto take = [&](size_t bytes) -> char* {
        char* r = p;
        p += (bytes + 255) & ~(size_t)255;
        return r;
    };
    float*          qbuf   = (float*)take((size_t)N_NODES * 256 * 4);
    unsigned short* kbuf   = (unsigned short*)take((size_t)N_NODES * 256 * 2);
    unsigned short* vbuf   = (unsigned short*)take((size_t)N_NODES * 256 * 2);
    unsigned short* xb     = (unsigned short*)take((size_t)N_NODES * 128 * 2);  // layer0 A / final x
    unsigned short* xb2    = (unsigned short*)take((size_t)N_NODES * 128 * 2);  // layer1 A
    unsigned short* hb     = (unsigned short*)take((size_t)N_NODES * 256 * 2);  // attn out bf16
    unsigned short* Wqkvp  = (unsigned short*)take((size_t)196608 * 2);         // packed qkv
    unsigned short* Wfp    = (unsigned short*)take((size_t)98304 * 2);          // packed [Wt;Wc]
    float*          Wc     = (float*)take(2 * 128 * 128 * 4);
    float*          bc     = (float*)take(2 * 128 * 4);
    int*            counts = (int*)take((size_t)N_NODES * 4);
    int*            offs   = (int*)take((size_t)(N_NODES + 1) * 4);
    int*            cursor = (int*)take((size_t)N_NODES * 4);
    int*            csr    = (int*)take((size_t)N_EDGES * 4);
    int*            bsum   = (int*)take((size_t)SCAN_BLOCKS * 4);
    int*            boff   = (int*)take((size_t)SCAN_BLOCKS * 4);
    float*          psum   = (float*)take(NGRAPH * 128 * 4);
    unsigned*       pmax   = (unsigned*)take(NGRAPH * 128 * 4);
    int*            pcnt   = (int*)take(NGRAPH * 4);

    const int EB = (N_EDGES + 255) / 256;          // 3125
    const int GB = (N_NODES + 127) / 128;          // 391  (MFMA GEMM blocks)
    const int PB = (N_NODES + 31) / 32;            // 1563 (pooling blocks)

    // ---- CSR build ----
    hipMemsetAsync(counts, 0, (size_t)N_NODES * 4, stream);
    degree_kernel<<<EB, 256, 0, stream>>>(ei, counts);
    block_sum_kernel<<<SCAN_BLOCKS, 256, 0, stream>>>(counts, bsum);
    scan_bsum_kernel<<<1, 256, 0, stream>>>(bsum, boff);
    block_scan_kernel<<<SCAN_BLOCKS, 256, 0, stream>>>(counts, boff, offs, cursor);
    scatter_kernel<<<EB, 256, 0, stream>>>(ei, cursor, csr);

    // ---- weight prep ----
    wc_kernel<<<128, 256, 0, stream>>>(Wsk, Wt, Wc);
    bc_kernel<<<1, 256, 0, stream>>>(bsk, Wt, bt, bc);
    pack_qkv_kernel<<<768, 256, 0, stream>>>(Wq, Wk, Wv, Wqkvp);
    pack_fused_kernel<<<384, 256, 0, stream>>>(Wt, Wc, Wfp);
    f2bf_kernel<<<(N_NODES * 32 + 255) / 256, 256, 0, stream>>>(x, xb, N_NODES * 32);

    // ---- layer 0 ----
    proj_mfma_kernel<<<GB, 256, 0, stream>>>(xb, Wqkvp, bq, bk, bv, qbuf, kbuf, vbuf);
    attn_kernel<<<N_NODES, 64, 0, stream>>>(qbuf, kbuf, vbuf, offs, csr, hb);
    out_mfma_kernel<<<GB, 256, 0, stream>>>(hb, xb, Wfp, bc, xb2);

    // ---- layer 1 ----
    proj_mfma_kernel<<<GB, 256, 0, stream>>>(xb2, Wqkvp + 98304, bq + 256, bk + 256, bv + 256,
                                             qbuf, kbuf, vbuf);
    attn_kernel<<<N_NODES, 64, 0, stream>>>(qbuf, kbuf, vbuf, offs, csr, hb);
    out_mfma_kernel<<<GB, 256, 0, stream>>>(hb, xb2, Wfp + 49152, bc + 128, xb);

    // ---- pooling (reads bf16 x, fp32 accumulate; counts via binary search) ----
    hipMemsetAsync(psum, 0, NGRAPH * 128 * 4, stream);
    hipMemsetAsync(pmax, 0, NGRAPH * 128 * 4, stream);
    graph_count_kernel<<<1, 64, 0, stream>>>(gi, pcnt);
    pool_accum_kernel<<<PB, 256, 0, stream>>>(xb, gi, psum, pmax);
    pool_final_kernel<<<(NGRAPH * 384 + 255) / 256, 256, 0, stream>>>(psum, pmax, pcnt, out);
}

// Round 6
// 635.215 us; speedup vs baseline: 3.2465x; 1.0051x over previous
//
#include <hip/hip_runtime.h>
#include <math.h>

#define N_NODES 50000
#define N_EDGES 800000
#define NGRAPH  64
#define SCAN_BLOCKS ((N_NODES + 255) / 256)   // 196

typedef __bf16 bf16x8 __attribute__((ext_vector_type(8)));
typedef float  f32x4  __attribute__((ext_vector_type(4)));

__device__ __forceinline__ unsigned short f2bf(float f) {
    unsigned u = __float_as_uint(f);
    u += 0x7fff + ((u >> 16) & 1);          // round-to-nearest-even
    return (unsigned short)(u >> 16);
}
__device__ __forceinline__ float bf2f(unsigned short u) {
    return __uint_as_float((unsigned)u << 16);
}

// ---------------------------------------------------------------------------
// CSR build
// ---------------------------------------------------------------------------
__global__ void degree_kernel(const int* __restrict__ ei, int* __restrict__ counts) {
    int e = blockIdx.x * 256 + threadIdx.x;
    if (e < N_EDGES) atomicAdd(&counts[ei[N_EDGES + e]], 1);
}

__global__ __launch_bounds__(256) void block_sum_kernel(const int* __restrict__ counts,
                                                        int* __restrict__ bsum) {
    int i = blockIdx.x * 256 + threadIdx.x;
    int v = (i < N_NODES) ? counts[i] : 0;
    #pragma unroll
    for (int o = 32; o >= 1; o >>= 1) v += __shfl_xor(v, o);
    __shared__ int ws[4];
    if ((threadIdx.x & 63) == 0) ws[threadIdx.x >> 6] = v;
    __syncthreads();
    if (threadIdx.x == 0) bsum[blockIdx.x] = ws[0] + ws[1] + ws[2] + ws[3];
}

__global__ __launch_bounds__(256) void scan_bsum_kernel(const int* __restrict__ bsum,
                                                        int* __restrict__ boff) {
    int t = threadIdx.x;
    int v = (t < SCAN_BLOCKS) ? bsum[t] : 0;
    int lane = t & 63, wid = t >> 6;
    int incl = v;
    #pragma unroll
    for (int o = 1; o < 64; o <<= 1) {
        int tv = __shfl_up(incl, o);
        if (lane >= o) incl += tv;
    }
    __shared__ int wsum[4];
    if (lane == 63) wsum[wid] = incl;
    __syncthreads();
    int add = 0;
    for (int w = 0; w < wid; w++) add += wsum[w];
    if (t < SCAN_BLOCKS) boff[t] = add + incl - v;   // exclusive
}

__global__ __launch_bounds__(256) void block_scan_kernel(const int* __restrict__ counts,
                                                         const int* __restrict__ boff,
                                                         int* __restrict__ offs,
                                                         int* __restrict__ cursor) {
    int i = blockIdx.x * 256 + threadIdx.x;
    int v = (i < N_NODES) ? counts[i] : 0;
    int lane = threadIdx.x & 63, wid = threadIdx.x >> 6;
    int incl = v;
    #pragma unroll
    for (int o = 1; o < 64; o <<= 1) {
        int tv = __shfl_up(incl, o);
        if (lane >= o) incl += tv;
    }
    __shared__ int wsum[4];
    if (lane == 63) wsum[wid] = incl;
    __syncthreads();
    int add = boff[blockIdx.x];
    for (int w = 0; w < wid; w++) add += wsum[w];
    if (i < N_NODES) {
        offs[i + 1] = add + incl;
        cursor[i]   = add + incl - v;
    }
    if (i == 0) offs[0] = 0;
}

__global__ void scatter_kernel(const int* __restrict__ ei, int* __restrict__ cursor,
                               int* __restrict__ csr) {
    int e = blockIdx.x * 256 + threadIdx.x;
    if (e < N_EDGES) {
        int d = ei[N_EDGES + e];
        int pos = atomicAdd(&cursor[d], 1);
        csr[pos] = ei[e];  // src
    }
}

// ---------------------------------------------------------------------------
// Skip-path fusion (fp32): Wc[l] = Ws[l] @ Wt[l], bc[l] = bs[l] @ Wt[l] + bt[l]
// ---------------------------------------------------------------------------
__global__ void wc_kernel(const float* __restrict__ Ws, const float* __restrict__ Wt,
                          float* __restrict__ Wc) {
    int idx = blockIdx.x * 256 + threadIdx.x;       // 2*128*128 = 32768
    int l = idx >> 14, ij = idx & 16383, i = ij >> 7, j = ij & 127;
    const float* a = Ws + (size_t)l * 32768;
    const float* b = Wt + (size_t)l * 32768;
    float s = 0.f;
    for (int k = 0; k < 256; k++) s = fmaf(a[i * 256 + k], b[k * 128 + j], s);
    Wc[idx] = s;
}

__global__ void bc_kernel(const float* __restrict__ bs, const float* __restrict__ Wt,
                          const float* __restrict__ bt, float* __restrict__ bc) {
    int idx = threadIdx.x;                           // 2 layers x 128
    int l = idx >> 7, j = idx & 127;
    const float* b = Wt + (size_t)l * 32768;
    float s = bt[l * 128 + j];
    for (int k = 0; k < 256; k++) s = fmaf(bs[l * 256 + k], b[k * 128 + j], s);
    bc[idx] = s;
}

// ---------------------------------------------------------------------------
// Weight packing into MFMA B-fragment layout (bf16, ks-major)
// ---------------------------------------------------------------------------
__global__ void pack_qkv_kernel(const float* __restrict__ Wq, const float* __restrict__ Wk,
                                const float* __restrict__ Wv, unsigned short* __restrict__ out) {
    int idx = blockIdx.x * 256 + threadIdx.x;        // 2*3*32768 = 196608
    if (idx >= 196608) return;
    int j = idx & 7, lane = (idx >> 3) & 63, ct = (idx >> 9) & 15, ks = (idx >> 13) & 3;
    int m3 = idx >> 15;                              // 0..5
    int l = m3 / 3, m = m3 % 3;
    int k = ks * 32 + ((lane >> 4) * 8) + j;
    int n = ct * 16 + (lane & 15);
    const float* W = (m == 0) ? Wq : (m == 1) ? Wk : Wv;
    out[idx] = f2bf(W[(size_t)l * 32768 + k * 256 + n]);
}

// fused [Wt;Wc] (K=384): KS=12 (ks 0..7 from Wt, 8..11 from Wc), CT=8
__global__ void pack_fused_kernel(const float* __restrict__ Wt, const float* __restrict__ Wc,
                                  unsigned short* __restrict__ out) {
    int idx = blockIdx.x * 256 + threadIdx.x;        // 2*49152 = 98304
    if (idx >= 98304) return;
    int l = idx / 49152, r = idx % 49152;
    int j = r & 7, lane = (r >> 3) & 63;
    int rest = r >> 9;
    int ct = rest & 7, ks = rest >> 3;               // ks 0..11
    int k = ks * 32 + ((lane >> 4) * 8) + j;
    int n = ct * 16 + (lane & 15);
    float v = (k < 256) ? Wt[(size_t)l * 32768 + k * 128 + n]
                        : Wc[(size_t)l * 16384 + (k - 256) * 128 + n];
    out[idx] = f2bf(v);
}

// fp32 -> bf16 elementwise (x input), 4 elems/thread
__global__ void f2bf_kernel(const float* __restrict__ in, unsigned short* __restrict__ out, int n4) {
    int i = blockIdx.x * 256 + threadIdx.x;
    if (i >= n4) return;
    float4 v = ((const float4*)in)[i];
    ushort4 o;
    o.x = f2bf(v.x); o.y = f2bf(v.y); o.z = f2bf(v.z); o.w = f2bf(v.w);
    ((ushort4*)out)[i] = o;
}

// ---------------------------------------------------------------------------
// MFMA q/k/v projection: [N,128]bf16 @ 3x[128,256] -> q fp32; k,v interleaved
// bf16 into kv rows of 512 shorts: [k(256) | v(256)].
// ---------------------------------------------------------------------------
__global__ __launch_bounds__(256) void proj_mfma_kernel(
    const unsigned short* __restrict__ xb, const unsigned short* __restrict__ Wp,
    const float* __restrict__ b0, const float* __restrict__ b1, const float* __restrict__ b2,
    float* __restrict__ oq, unsigned short* __restrict__ kv) {
    int w = threadIdx.x >> 6, lane = threadIdx.x & 63;
    int quad = lane >> 4, lr = lane & 15;
    int rbase = blockIdx.x * 128 + w * 32;

    bf16x8 a[2][4];
    #pragma unroll
    for (int s = 0; s < 2; s++) {
        int r = rbase + s * 16 + lr;
        if (r > N_NODES - 1) r = N_NODES - 1;
        const unsigned short* xr = xb + (size_t)r * 128 + quad * 8;
        #pragma unroll
        for (int ks = 0; ks < 4; ks++) a[s][ks] = *(const bf16x8*)(xr + ks * 32);
    }

    const float* bias[3] = {b0, b1, b2};
    for (int mm = 0; mm < 3; mm++) {
        const unsigned short* wp = Wp + mm * 32768;
        int off = (mm == 2) ? 256 : 0;               // v goes to the second half
        for (int ct = 0; ct < 16; ct++) {
            f32x4 c0 = {0.f, 0.f, 0.f, 0.f}, c1 = {0.f, 0.f, 0.f, 0.f};
            #pragma unroll
            for (int ks = 0; ks < 4; ks++) {
                bf16x8 b = *(const bf16x8*)(wp + (size_t)((ks * 16 + ct) * 64 + lane) * 8);
                c0 = __builtin_amdgcn_mfma_f32_16x16x32_bf16(a[0][ks], b, c0, 0, 0, 0);
                c1 = __builtin_amdgcn_mfma_f32_16x16x32_bf16(a[1][ks], b, c1, 0, 0, 0);
            }
            int col = ct * 16 + lr;
            float bb = bias[mm][col];
            #pragma unroll
            for (int r = 0; r < 4; r++) {
                int row0 = rbase + quad * 4 + r;
                int row1 = rbase + 16 + quad * 4 + r;
                float v0 = c0[r] + bb, v1 = c1[r] + bb;
                if (mm == 0) {
                    if (row0 < N_NODES) oq[(size_t)row0 * 256 + col] = v0;
                    if (row1 < N_NODES) oq[(size_t)row1 * 256 + col] = v1;
                } else {
                    if (row0 < N_NODES) kv[(size_t)row0 * 512 + off + col] = f2bf(v0);
                    if (row1 < N_NODES) kv[(size_t)row1 * 512 + off + col] = f2bf(v1);
                }
            }
        }
    }
}

// ---------------------------------------------------------------------------
// MFMA output linear: x_next = relu([h|x] @ [Wt;Wc] + bc); writes bf16 only
// ---------------------------------------------------------------------------
__global__ __launch_bounds__(256) void out_mfma_kernel(
    const unsigned short* __restrict__ hb, const unsigned short* __restrict__ xb,
    const unsigned short* __restrict__ Wfp, const float* __restrict__ bc,
    unsigned short* __restrict__ xbout) {
    int w = threadIdx.x >> 6, lane = threadIdx.x & 63;
    int quad = lane >> 4, lr = lane & 15;
    int rbase = blockIdx.x * 128 + w * 32;
    int r0 = rbase + lr;      if (r0 > N_NODES - 1) r0 = N_NODES - 1;
    int r1 = rbase + 16 + lr; if (r1 > N_NODES - 1) r1 = N_NODES - 1;

    f32x4 acc[8][2];
    #pragma unroll
    for (int ct = 0; ct < 8; ct++) {
        acc[ct][0] = (f32x4){0.f, 0.f, 0.f, 0.f};
        acc[ct][1] = (f32x4){0.f, 0.f, 0.f, 0.f};
    }

    #pragma unroll 4
    for (int ks = 0; ks < 12; ks++) {
        bf16x8 a0, a1;
        if (ks < 8) {
            a0 = *(const bf16x8*)(hb + (size_t)r0 * 256 + ks * 32 + quad * 8);
            a1 = *(const bf16x8*)(hb + (size_t)r1 * 256 + ks * 32 + quad * 8);
        } else {
            a0 = *(const bf16x8*)(xb + (size_t)r0 * 128 + (ks - 8) * 32 + quad * 8);
            a1 = *(const bf16x8*)(xb + (size_t)r1 * 128 + (ks - 8) * 32 + quad * 8);
        }
        #pragma unroll
        for (int ct = 0; ct < 8; ct++) {
            bf16x8 b = *(const bf16x8*)(Wfp + (size_t)((ks * 8 + ct) * 64 + lane) * 8);
            acc[ct][0] = __builtin_amdgcn_mfma_f32_16x16x32_bf16(a0, b, acc[ct][0], 0, 0, 0);
            acc[ct][1] = __builtin_amdgcn_mfma_f32_16x16x32_bf16(a1, b, acc[ct][1], 0, 0, 0);
        }
    }

    #pragma unroll
    for (int ct = 0; ct < 8; ct++) {
        int col = ct * 16 + lr;
        float bb = bc[col];
        #pragma unroll
        for (int r = 0; r < 4; r++) {
            int row0 = rbase + quad * 4 + r;
            if (row0 < N_NODES)
                xbout[(size_t)row0 * 128 + col] = f2bf(fmaxf(acc[ct][0][r] + bb, 0.f));
            int row1 = rbase + 16 + quad * 4 + r;
            if (row1 < N_NODES)
                xbout[(size_t)row1 * 128 + col] = f2bf(fmaxf(acc[ct][1][r] + bb, 0.f));
        }
    }
}

// ---------------------------------------------------------------------------
// Attention, single pass, no max-subtraction (logit |l| <~ 3 << 88: exp-safe;
// softmax is shift-invariant so result matches the reference).
// One wave per dst node; lane i holds row elems [4i,4i+4); lanes 0..31 =
// head0, 32..63 = head1. After the intra-32 butterfly each lane holds its OWN
// head's logit, so no cross-half exchange, no LDS, no second pass.
// kv rows: 512 shorts = [k(256) | v(256)] bf16.
// ---------------------------------------------------------------------------
__global__ __launch_bounds__(64) void attn_kernel(
    const float* __restrict__ q, const unsigned short* __restrict__ kv,
    const int* __restrict__ offs, const int* __restrict__ csr,
    unsigned short* __restrict__ hout) {
    const float SCALE = 0.08838834764831845f;  // 1/sqrt(128)
    int n = blockIdx.x, lane = threadIdx.x;
    float4 q4 = ((const float4*)(q + (size_t)n * 256))[lane];
    int beg = offs[n], end = offs[n + 1];

    float4 acc = make_float4(0.f, 0.f, 0.f, 0.f);
    float d = 0.f;

    auto cvt = [](ushort4 u) {
        return make_float4(bf2f(u.x), bf2f(u.y), bf2f(u.z), bf2f(u.w));
    };

    int j = beg;
    for (; j + 4 <= end; j += 4) {
        int s0 = csr[j], s1 = csr[j + 1], s2 = csr[j + 2], s3 = csr[j + 3];
        const ushort4* r0 = (const ushort4*)(kv + (size_t)s0 * 512);
        const ushort4* r1 = (const ushort4*)(kv + (size_t)s1 * 512);
        const ushort4* r2 = (const ushort4*)(kv + (size_t)s2 * 512);
        const ushort4* r3 = (const ushort4*)(kv + (size_t)s3 * 512);
        ushort4 ku0 = r0[lane], vu0 = r0[64 + lane];
        ushort4 ku1 = r1[lane], vu1 = r1[64 + lane];
        ushort4 ku2 = r2[lane], vu2 = r2[64 + lane];
        ushort4 ku3 = r3[lane], vu3 = r3[64 + lane];
        float4 k0 = cvt(ku0), k1 = cvt(ku1), k2 = cvt(ku2), k3 = cvt(ku3);
        float p0 = q4.x * k0.x + q4.y * k0.y + q4.z * k0.z + q4.w * k0.w;
        float p1 = q4.x * k1.x + q4.y * k1.y + q4.z * k1.z + q4.w * k1.w;
        float p2 = q4.x * k2.x + q4.y * k2.y + q4.z * k2.z + q4.w * k2.w;
        float p3 = q4.x * k3.x + q4.y * k3.y + q4.z * k3.z + q4.w * k3.w;
        #pragma unroll
        for (int o = 16; o >= 1; o >>= 1) {
            p0 += __shfl_xor(p0, o);
            p1 += __shfl_xor(p1, o);
            p2 += __shfl_xor(p2, o);
            p3 += __shfl_xor(p3, o);
        }
        float e0 = __expf(p0 * SCALE), e1 = __expf(p1 * SCALE);
        float e2 = __expf(p2 * SCALE), e3 = __expf(p3 * SCALE);
        d += (e0 + e1) + (e2 + e3);
        float4 v0 = cvt(vu0), v1 = cvt(vu1), v2 = cvt(vu2), v3 = cvt(vu3);
        acc.x = fmaf(e0, v0.x, fmaf(e1, v1.x, fmaf(e2, v2.x, fmaf(e3, v3.x, acc.x))));
        acc.y = fmaf(e0, v0.y, fmaf(e1, v1.y, fmaf(e2, v2.y, fmaf(e3, v3.y, acc.y))));
        acc.z = fmaf(e0, v0.z, fmaf(e1, v1.z, fmaf(e2, v2.z, fmaf(e3, v3.z, acc.z))));
        acc.w = fmaf(e0, v0.w, fmaf(e1, v1.w, fmaf(e2, v2.w, fmaf(e3, v3.w, acc.w))));
    }
    for (; j < end; j++) {
        int s = csr[j];
        const ushort4* r = (const ushort4*)(kv + (size_t)s * 512);
        ushort4 ku = r[lane], vu = r[64 + lane];
        float4 k4 = cvt(ku);
        float p = q4.x * k4.x + q4.y * k4.y + q4.z * k4.z + q4.w * k4.w;
        #pragma unroll
        for (int o = 16; o >= 1; o >>= 1) p += __shfl_xor(p, o);
        float e = __expf(p * SCALE);
        d += e;
        float4 v4 = cvt(vu);
        acc.x = fmaf(e, v4.x, acc.x);
        acc.y = fmaf(e, v4.y, acc.y);
        acc.z = fmaf(e, v4.z, acc.z);
        acc.w = fmaf(e, v4.w, acc.w);
    }

    float inv = 1.f / (d + 1e-16f);
    ushort4 hv;
    hv.x = f2bf(acc.x * inv);
    hv.y = f2bf(acc.y * inv);
    hv.z = f2bf(acc.z * inv);
    hv.w = f2bf(acc.w * inv);
    ((ushort4*)(hout + (size_t)n * 256))[lane] = hv;
}

// ---------------------------------------------------------------------------
// Per-graph node counts via binary search over the SORTED graph_indices.
// ---------------------------------------------------------------------------
__global__ __launch_bounds__(64) void graph_count_kernel(const int* __restrict__ gi,
                                                         int* __restrict__ pcnt) {
    int g = threadIdx.x;   // 0..63
    auto lb = [&](int target) {
        int lo = 0, hi = N_NODES;
        while (lo < hi) {
            int mid = (lo + hi) >> 1;
            if (gi[mid] < target) lo = mid + 1;
            else hi = mid;
        }
        return lo;
    };
    int a = lb(g), b = lb(g + 1);
    pcnt[g] = b - a;
}

// ---------------------------------------------------------------------------
// Pooling from bf16 x. gi sorted -> per-run local accumulate, one atomic per
// (col, run). relu output >= 0 => uint atomicMax order-correct, 0 is identity.
// ---------------------------------------------------------------------------
__global__ __launch_bounds__(256) void pool_accum_kernel(
    const unsigned short* __restrict__ xb, const int* __restrict__ gi,
    float* __restrict__ psum, unsigned* __restrict__ pmax) {
    int n0 = blockIdx.x * 32;
    int col = threadIdx.x & 127, half = threadIdx.x >> 7;
    float sum = 0.f, mx = 0.f;
    int first = n0 + half;
    if (first >= N_NODES) return;
    int cur_g = gi[first];
    for (int r = half; r < 32; r += 2) {
        int n = n0 + r;
        if (n >= N_NODES) break;
        int g = gi[n];
        if (g != cur_g) {
            atomicAdd(&psum[cur_g * 128 + col], sum);
            atomicMax(&pmax[cur_g * 128 + col], __float_as_uint(mx));
            sum = 0.f; mx = 0.f; cur_g = g;
        }
        float v = bf2f(xb[(size_t)n * 128 + col]);
        sum += v;
        mx = fmaxf(mx, v);
    }
    atomicAdd(&psum[cur_g * 128 + col], sum);
    atomicMax(&pmax[cur_g * 128 + col], __float_as_uint(mx));
}

__global__ void pool_final_kernel(const float* __restrict__ psum, const unsigned* __restrict__ pmax,
                                  const int* __restrict__ pcnt, float* __restrict__ out) {
    int idx = blockIdx.x * 256 + threadIdx.x;
    if (idx >= NGRAPH * 384) return;
    int g = idx / 384, c = idx % 384;
    float r;
    if (c < 128)       r = __uint_as_float(pmax[g * 128 + c]);
    else if (c < 256)  r = psum[g * 128 + (c - 128)] / fmaxf((float)pcnt[g], 1.f);
    else               r = psum[g * 128 + (c - 256)];
    out[idx] = r;
}

// ---------------------------------------------------------------------------
extern "C" void kernel_launch(void* const* d_in, const int* in_sizes, int n_in,
                              void* d_out, int out_size, void* d_ws, size_t ws_size,
                              hipStream_t stream) {
    const float* x   = (const float*)d_in[0];
    const int*   ei  = (const int*)d_in[1];
    const int*   gi  = (const int*)d_in[2];
    const float* Wq  = (const float*)d_in[3];
    const float* bq  = (const float*)d_in[4];
    const float* Wk  = (const float*)d_in[5];
    const float* bk  = (const float*)d_in[6];
    const float* Wv  = (const float*)d_in[7];
    const float* bv  = (const float*)d_in[8];
    const float* Wsk = (const float*)d_in[9];
    const float* bsk = (const float*)d_in[10];
    const float* Wt  = (const float*)d_in[11];
    const float* bt  = (const float*)d_in[12];
    float* out = (float*)d_out;

    char* p = (char*)d_ws;
    auto take = [&](size_t bytes) -> char* {
        char* r = p;
        p += (bytes + 255) & ~(size_t)255;
        return r;
    };
    float*          qbuf   = (float*)take((size_t)N_NODES * 256 * 4);
    unsigned short* kvbuf  = (unsigned short*)take((size_t)N_NODES * 512 * 2);  // [k|v] rows
    unsigned short* xb     = (unsigned short*)take((size_t)N_NODES * 128 * 2);  // layer0 A / final x
    unsigned short* xb2    = (unsigned short*)take((size_t)N_NODES * 128 * 2);  // layer1 A
    unsigned short* hb     = (unsigned short*)take((size_t)N_NODES * 256 * 2);  // attn out bf16
    unsigned short* Wqkvp  = (unsigned short*)take((size_t)196608 * 2);         // packed qkv
    unsigned short* Wfp    = (unsigned short*)take((size_t)98304 * 2);          // packed [Wt;Wc]
    float*          Wc     = (float*)take(2 * 128 * 128 * 4);
    float*          bc     = (float*)take(2 * 128 * 4);
    int*            counts = (int*)take((size_t)N_NODES * 4);
    int*            offs   = (int*)take((size_t)(N_NODES + 1) * 4);
    int*            cursor = (int*)take((size_t)N_NODES * 4);
    int*            csr    = (int*)take((size_t)N_EDGES * 4);
    int*            bsum   = (int*)take((size_t)SCAN_BLOCKS * 4);
    int*            boff   = (int*)take((size_t)SCAN_BLOCKS * 4);
    float*          psum   = (float*)take(NGRAPH * 128 * 4);
    unsigned*       pmax   = (unsigned*)take(NGRAPH * 128 * 4);
    int*            pcnt   = (int*)take(NGRAPH * 4);

    const int EB = (N_EDGES + 255) / 256;          // 3125
    const int GB = (N_NODES + 127) / 128;          // 391  (MFMA GEMM blocks)
    const int PB = (N_NODES + 31) / 32;            // 1563 (pooling blocks)

    // ---- CSR build ----
    hipMemsetAsync(counts, 0, (size_t)N_NODES * 4, stream);
    degree_kernel<<<EB, 256, 0, stream>>>(ei, counts);
    block_sum_kernel<<<SCAN_BLOCKS, 256, 0, stream>>>(counts, bsum);
    scan_bsum_kernel<<<1, 256, 0, stream>>>(bsum, boff);
    block_scan_kernel<<<SCAN_BLOCKS, 256, 0, stream>>>(counts, boff, offs, cursor);
    scatter_kernel<<<EB, 256, 0, stream>>>(ei, cursor, csr);

    // ---- weight prep ----
    wc_kernel<<<128, 256, 0, stream>>>(Wsk, Wt, Wc);
    bc_kernel<<<1, 256, 0, stream>>>(bsk, Wt, bt, bc);
    pack_qkv_kernel<<<768, 256, 0, stream>>>(Wq, Wk, Wv, Wqkvp);
    pack_fused_kernel<<<384, 256, 0, stream>>>(Wt, Wc, Wfp);
    f2bf_kernel<<<(N_NODES * 32 + 255) / 256, 256, 0, stream>>>(x, xb, N_NODES * 32);

    // ---- layer 0 ----
    proj_mfma_kernel<<<GB, 256, 0, stream>>>(xb, Wqkvp, bq, bk, bv, qbuf, kvbuf);
    attn_kernel<<<N_NODES, 64, 0, stream>>>(qbuf, kvbuf, offs, csr, hb);
    out_mfma_kernel<<<GB, 256, 0, stream>>>(hb, xb, Wfp, bc, xb2);

    // ---- layer 1 ----
    proj_mfma_kernel<<<GB, 256, 0, stream>>>(xb2, Wqkvp + 98304, bq + 256, bk + 256, bv + 256,
                                             qbuf, kvbuf);
    attn_kernel<<<N_NODES, 64, 0, stream>>>(qbuf, kvbuf, offs, csr, hb);
    out_mfma_kernel<<<GB, 256, 0, stream>>>(hb, xb2, Wfp + 49152, bc + 128, xb);

    // ---- pooling (reads bf16 x, fp32 accumulate; counts via binary search) ----
    hipMemsetAsync(psum, 0, NGRAPH * 128 * 4, stream);
    hipMemsetAsync(pmax, 0, NGRAPH * 128 * 4, stream);
    graph_count_kernel<<<1, 64, 0, stream>>>(gi, pcnt);
    pool_accum_kernel<<<PB, 256, 0, stream>>>(xb, gi, psum, pmax);
    pool_final_kernel<<<(NGRAPH * 384 + 255) / 256, 256, 0, stream>>>(psum, pmax, pcnt, out);
}